// Round 13
// baseline (386.876 us; speedup 1.0000x reference)
//
#include <hip/hip_runtime.h>
#include <math.h>

// ---------- float4 / bf16 helpers ----------
static __device__ __forceinline__ float4 f4s(float v){ return make_float4(v,v,v,v); }
static __device__ __forceinline__ float4 f4add(float4 a, float4 b){ return make_float4(a.x+b.x,a.y+b.y,a.z+b.z,a.w+b.w); }
static __device__ __forceinline__ float4 f4max(float4 a, float4 b){ return make_float4(fmaxf(a.x,b.x),fmaxf(a.y,b.y),fmaxf(a.z,b.z),fmaxf(a.w,b.w)); }
static __device__ __forceinline__ float4 f4scale(float4 a, float s){ return make_float4(a.x*s,a.y*s,a.z*s,a.w*s); }
static __device__ __forceinline__ float4 f4fma(float4 acc, float s, float4 b){
  acc.x += s*b.x; acc.y += s*b.y; acc.z += s*b.z; acc.w += s*b.w; return acc;
}
static __device__ __forceinline__ float4 f4relu(float4 a){ return f4max(a, f4s(0.f)); }
static __device__ __forceinline__ float4 f4leaky(float4 a){
  return make_float4(a.x>0.f?a.x:0.2f*a.x, a.y>0.f?a.y:0.2f*a.y, a.z>0.f?a.z:0.2f*a.z, a.w>0.f?a.w:0.2f*a.w);
}
static __device__ __forceinline__ float4 f4expf(float4 a){ return make_float4(__expf(a.x),__expf(a.y),__expf(a.z),__expf(a.w)); }
static __device__ __forceinline__ unsigned short f2bf(float f){
  unsigned int u = __float_as_uint(f);
  unsigned int r = (u + 0x7fffu + ((u >> 16) & 1u)) >> 16;
  return (unsigned short)r;
}
static __device__ __forceinline__ ushort4 f2bf4(float4 f){
  ushort4 r; r.x=f2bf(f.x); r.y=f2bf(f.y); r.z=f2bf(f.z); r.w=f2bf(f.w); return r;
}
// bf16x4 (as uint2) -> float4 : 4 VALU ops
static __device__ __forceinline__ float4 bfu2f4(uint2 u){
  return make_float4(__uint_as_float(u.x << 16), __uint_as_float(u.x & 0xffff0000u),
                     __uint_as_float(u.y << 16), __uint_as_float(u.y & 0xffff0000u));
}
static __device__ __forceinline__ float4 bfu2f4_lo(uint4 u){ return bfu2f4(make_uint2(u.x, u.y)); }
static __device__ __forceinline__ float4 bfu2f4_hi(uint4 u){ return bfu2f4(make_uint2(u.z, u.w)); }

typedef __attribute__((ext_vector_type(8))) unsigned short u16x8;
static __device__ __forceinline__ u16x8 f2bf8(float4 a, float4 b){
  u16x8 r;
  r[0]=f2bf(a.x); r[1]=f2bf(a.y); r[2]=f2bf(a.z); r[3]=f2bf(a.w);
  r[4]=f2bf(b.x); r[5]=f2bf(b.y); r[6]=f2bf(b.z); r[7]=f2bf(b.w);
  return r;
}
// reduce two float4 across 2 groups at lane stride 8
static __device__ __forceinline__ void red2(float4& a, float4& b){
  a.x += __shfl_xor(a.x, 8); a.y += __shfl_xor(a.y, 8);
  a.z += __shfl_xor(a.z, 8); a.w += __shfl_xor(a.w, 8);
  b.x += __shfl_xor(b.x, 8); b.y += __shfl_xor(b.y, 8);
  b.z += __shfl_xor(b.z, 8); b.w += __shfl_xor(b.w, 8);
}

// ---------- MFMA types ----------
typedef __attribute__((ext_vector_type(8))) short bf16x8;   // 8 bf16 = 4 VGPRs
typedef __attribute__((ext_vector_type(4))) float f32x4;

// ---------- CSR build ----------
__global__ __launch_bounds__(256) void k_count(const int* __restrict__ dst, int* __restrict__ cnt, int E){
  int t = blockIdx.x*256 + threadIdx.x;
  if (t < E) atomicAdd(&cnt[dst[t]], 1);
}
__global__ __launch_bounds__(256) void k_scan1(const int* __restrict__ cnt, int* __restrict__ excl,
                                               int* __restrict__ bsum, int n){
  __shared__ int sc[256];
  int t = threadIdx.x; int i = blockIdx.x*256 + t;
  int v = (i<n)?cnt[i]:0;
  sc[t]=v; __syncthreads();
  for (int o=1;o<256;o<<=1){ int a=(t>=o)?sc[t-o]:0; __syncthreads(); sc[t]+=a; __syncthreads(); }
  if (i<n) excl[i] = sc[t]-v;
  if (t==255) bsum[blockIdx.x] = sc[t];
}
// scan of block sums + (fused) GAT attention basis vectors Vs/Vd
__global__ __launch_bounds__(256) void k_scan2v(int* __restrict__ bsum, int nb,
                                                const float* __restrict__ Wg, const float* __restrict__ as,
                                                const float* __restrict__ ad, float* __restrict__ Vs,
                                                float* __restrict__ Vd){
  __shared__ int sc[256];
  int t = threadIdx.x;
  int v = (t<nb)?bsum[t]:0;
  sc[t]=v; __syncthreads();
  for (int o=1;o<256;o<<=1){ int a=(t>=o)?sc[t-o]:0; __syncthreads(); sc[t]+=a; __syncthreads(); }
  if (t<nb) bsum[t] = sc[t]-v;
  // Vs[h][k] = sum_c W_gat[k][h*64+c]*att_s[h][c]  (t = h*64+k)
  int h = t >> 6, k = t & 63;
  float s = 0.f, d = 0.f;
  const float* wr = Wg + (size_t)k*256 + h*64;
  const float* ar = as + h*64;
  const float* dr = ad + h*64;
  for (int c = 0; c < 64; ++c){ float w = wr[c]; s += w*ar[c]; d += w*dr[c]; }
  Vs[t] = s; Vd[t] = d;
}
__global__ __launch_bounds__(256) void k_scan3(const int* __restrict__ cnt, const int* __restrict__ excl,
                                               const int* __restrict__ bsum, int* __restrict__ offs,
                                               int* __restrict__ head, float* __restrict__ dinv, int n, int E){
  int i = blockIdx.x*256 + threadIdx.x;
  if (i < n){
    int o = excl[i] + bsum[blockIdx.x];
    offs[i] = o; head[i] = o;
    dinv[i] = rsqrtf((float)cnt[i] + 1.0f);   // deg includes self-loop
    if (i == 0) offs[n] = E;
  }
}
__global__ __launch_bounds__(256) void k_fill(const int* __restrict__ src, const int* __restrict__ dst,
                                              int* __restrict__ head, int* __restrict__ csr, int E){
  int t = blockIdx.x*256 + threadIdx.x;
  if (t < E){ int p = atomicAdd(&head[dst[t]], 1); csr[p] = src[t]; }
}

// ---------- GAT logits from H: D[nd][h] = H[nd].Vs[h], D[nd][4+h] = H[nd].Vd[h] ----------
__global__ __launch_bounds__(256) void k_asdh(const unsigned short* __restrict__ Hh,
                                              const float* __restrict__ Vs, const float* __restrict__ Vd,
                                              float* __restrict__ D, int n){
  __shared__ float vs[256], vd[256];
  int t = threadIdx.x;
  vs[t] = Vs[t]; vd[t] = Vd[t];
  __syncthreads();
  int idx = blockIdx.x*256 + t;
  if (idx >= n*4) return;
  int nd = idx >> 2, h = idx & 3;
  const unsigned short* hr = Hh + (size_t)nd*64;
  const float* vsr = vs + h*64;
  const float* vdr = vd + h*64;
  float s = 0.f, d = 0.f;
  #pragma unroll
  for (int k = 0; k < 8; ++k){
    uint4 u = *(const uint4*)(hr + k*8);
    float4 lo = bfu2f4_lo(u), hi = bfu2f4_hi(u);
    const float* a = vsr + k*8;
    const float* b = vdr + k*8;
    s += lo.x*a[0]+lo.y*a[1]+lo.z*a[2]+lo.w*a[3] + hi.x*a[4]+hi.y*a[5]+hi.z*a[6]+hi.w*a[7];
    d += lo.x*b[0]+lo.y*b[1]+lo.z*b[2]+lo.w*b[3] + hi.x*b[4]+hi.y*b[5]+hi.z*b[6]+hi.w*b[7];
  }
  D[(size_t)nd*8 + h]     = s;
  D[(size_t)nd*8 + 4 + h] = d;
}

// ---------- MFMA GEMM: out[n,Cout](bf16) = in[n,K] @ W, W f32->bf16 staged in LDS ----------
template<int K, int Cout, bool IBF16, bool SCALE, bool DUAL, bool H4, bool BRELU>
__global__ __launch_bounds__(256) void k_mgemm(const void* __restrict__ in, int ldin,
                                               const float* __restrict__ Wa, int ldwa,
                                               const float* __restrict__ Wb, int ldwb,
                                               unsigned short* __restrict__ out, int ldout,
                                               int n, const float* __restrict__ rowscale,
                                               const float* __restrict__ bias){
  constexpr int CC = Cout >> 4;       // 16-col chunks
  constexpr int KB = K >> 5;          // 32-k blocks
  constexpr int NH = H4 ? 4 : 1;
  extern __shared__ unsigned short wb[];
  int tid = threadIdx.x;
  constexpr int nslots = KB*CC*64;
  for (int s = tid; s < nslots; s += 256){
    int l = s & 63;
    int f = s >> 6;                   // frag = kb*CC + cc
    int cc = f % CC, kb = f / CC;
    int c  = cc*16 + (l & 15);
    int kr = kb*32 + ((l >> 4) << 3);
    const float* wp; int ld;
    if (DUAL && c >= (Cout/2)){ wp = Wb + (size_t)kr*ldwb + (c - Cout/2); ld = ldwb; }
    else                      { wp = Wa + (size_t)kr*ldwa + c;            ld = ldwa; }
    unsigned short* dp = &wb[s*8];
    #pragma unroll
    for (int j = 0; j < 8; ++j) dp[j] = f2bf(wp[(size_t)j*ld]);
  }
  __syncthreads();
  int wv = tid >> 6, l = tid & 63;
  int lrow = l & 15;
  int lk = (l >> 4) << 3;
  int ngrp = (n + 63) >> 6;
  const unsigned short* inb = (const unsigned short*)in;
  const float* inf = (const float*)in;
  for (int g = blockIdx.x; g < ngrp; g += gridDim.x){
    int r0 = (g << 6) + (wv << 4);
    int m = r0 + lrow;
    bf16x8 afr[NH][KB];
    #pragma unroll
    for (int h = 0; h < NH; ++h){
      #pragma unroll
      for (int kb = 0; kb < KB; ++kb){
        bf16x8 a = {0,0,0,0,0,0,0,0};
        if (m < n){
          int off = (H4 ? h*64 : 0) + kb*32 + lk;
          if (IBF16){
            a = *(const bf16x8*)(inb + (size_t)m*ldin + off);
          } else {
            const float* p = inf + (size_t)m*ldin + off;
            float4 f0 = *(const float4*)p;
            float4 f1 = *(const float4*)(p + 4);
            a[0]=(short)f2bf(f0.x); a[1]=(short)f2bf(f0.y); a[2]=(short)f2bf(f0.z); a[3]=(short)f2bf(f0.w);
            a[4]=(short)f2bf(f1.x); a[5]=(short)f2bf(f1.y); a[6]=(short)f2bf(f1.z); a[7]=(short)f2bf(f1.w);
          }
        }
        afr[h][kb] = a;
      }
    }
    int rbase = r0 + ((l >> 4) << 2);
    float sc[4];
    if (SCALE){
      #pragma unroll
      for (int r = 0; r < 4; ++r) sc[r] = (rbase + r < n) ? rowscale[rbase + r] : 0.f;
    }
    #pragma unroll
    for (int cc = 0; cc < CC; ++cc){
      f32x4 acc = {0.f, 0.f, 0.f, 0.f};
      constexpr int hstep = H4 ? 1 : 0;
      int hh = hstep ? (cc >> 2) : 0;
      #pragma unroll
      for (int kb = 0; kb < KB; ++kb){
        bf16x8 b = *(const bf16x8*)&wb[((kb*CC + cc)*64 + l)*8];
        acc = __builtin_amdgcn_mfma_f32_16x16x32_bf16(afr[hh][kb], b, acc, 0, 0, 0);
      }
      int c = cc*16 + lrow;
      float bv = BRELU ? bias[c] : 0.f;
      #pragma unroll
      for (int r = 0; r < 4; ++r){
        int rr = rbase + r;
        if (rr < n){
          float v = acc[r];
          if (SCALE) v *= sc[r];
          if (BRELU) v = fmaxf(v + bv, 0.f);
          out[(size_t)rr*ldout + c] = f2bf(v);
        }
      }
    }
  }
}

// ---------- GCN aggregation: 4 nodes/wave, 16 lanes/node = 2 edge-groups x 8 lanes ----------
// A0 rows pre-scaled by dinv[src]; H = relu(dinv_d*(sum+self) + b), bf16 out.
__global__ __launch_bounds__(256) void k_gcn(const unsigned short* __restrict__ h0, const float* __restrict__ dinv,
                                             const float* __restrict__ b, const int* __restrict__ offs,
                                             const int* __restrict__ csr, unsigned short* __restrict__ h, int n){
  int l = threadIdx.x & 63;
  int node = (((blockIdx.x*256 + threadIdx.x) >> 6) << 2) + (l >> 4);
  int l15 = l & 15;
  int grp = l15 >> 3, sub = l15 & 7;
  bool ok = node < n;
  int beg = 0, end = 0;
  float di = 0.f;
  if (ok){ beg = offs[node]; end = offs[node+1]; di = dinv[node]; }
  float4 aL0 = f4s(0.f), aH0 = f4s(0.f), aL1 = f4s(0.f), aH1 = f4s(0.f);
  int i = beg + grp;
  for (; i + 2 < end; i += 4){
    int s0 = csr[i], s1 = csr[i+2];
    uint4 u0 = *(const uint4*)(h0 + (size_t)s0*64 + (sub<<3));
    uint4 u1 = *(const uint4*)(h0 + (size_t)s1*64 + (sub<<3));
    aL0 = f4add(aL0, bfu2f4_lo(u0)); aH0 = f4add(aH0, bfu2f4_hi(u0));
    aL1 = f4add(aL1, bfu2f4_lo(u1)); aH1 = f4add(aH1, bfu2f4_hi(u1));
  }
  if (i < end){
    int s0 = csr[i];
    uint4 u0 = *(const uint4*)(h0 + (size_t)s0*64 + (sub<<3));
    aL0 = f4add(aL0, bfu2f4_lo(u0)); aH0 = f4add(aH0, bfu2f4_hi(u0));
  }
  float4 aL = f4add(aL0, aL1), aH = f4add(aH0, aH1);
  red2(aL, aH);
  if (ok && grp == 0){
    uint4 us = *(const uint4*)(h0 + (size_t)node*64 + (sub<<3));   // self (pre-scaled)
    aL = f4add(aL, bfu2f4_lo(us)); aH = f4add(aH, bfu2f4_hi(us));
    float4 b0 = *(const float4*)(b + (sub<<3));
    float4 b1 = *(const float4*)(b + (sub<<3) + 4);
    float4 r0 = f4relu(f4fma(b0, di, aL));
    float4 r1 = f4relu(f4fma(b1, di, aH));
    *(u16x8*)(h + (size_t)node*64 + (sub<<3)) = f2bf8(r0, r1);
  }
}

// ---------- fused GAT softmax + H-domain aggregation: 2 nodes/wave ----------
// Half-wave (32 lanes) per node; phase C = 2 edge-groups x 16 lanes per node.
// Each edge's H row read ONCE (uint2/lane), FMA'd into 4 per-head accumulators.
// No max-shift: logits are O(+-3); softmax is shift-invariant.
#define GAT_CAP 128
__global__ __launch_bounds__(256) void k_gat2(const float* __restrict__ D, const unsigned short* __restrict__ Hh,
                                              const int* __restrict__ offs, const int* __restrict__ csr,
                                              unsigned short* __restrict__ Y, int n){
  __shared__ float wl[8][GAT_CAP*4];
  __shared__ int   sl[8][GAT_CAP];
  int hw = threadIdx.x >> 5;                 // half-wave index in block (0..7)
  int node = (blockIdx.x*256 + threadIdx.x) >> 5;
  int l5 = threadIdx.x & 31;
  if (node >= n) return;
  int beg = offs[node], end = offs[node+1];
  int deg = end - beg;
  float4 ed  = *(const float4*)(D + (size_t)node*8 + 4);
  float4 es0 = *(const float4*)(D + (size_t)node*8);
  float4 wself = f4expf(f4leaky(f4add(es0, ed)));
  // phase A: per-edge exp weights + src byte-offset -> LDS (first GAT_CAP), z accumulation (all)
  float4 z4 = f4s(0.f);
  for (int i = beg + l5; i < end; i += 32){
    int s = csr[i];
    float4 w = f4expf(f4leaky(f4add(*(const float4*)(D + (size_t)s*8), ed)));
    int li = i - beg;
    if (li < GAT_CAP){ *(float4*)&wl[hw][li<<2] = w; sl[hw][li] = s << 7; }  // 128 B per H row
    z4 = f4add(z4, w);
  }
  // 32-lane butterfly (stays within each half-wave)
  for (int m = 1; m < 32; m <<= 1){
    z4.x += __shfl_xor(z4.x, m); z4.y += __shfl_xor(z4.y, m);
    z4.z += __shfl_xor(z4.z, m); z4.w += __shfl_xor(z4.w, m);
  }
  z4 = f4add(z4, wself);
  // phase C: 2 edge-groups x 16 lanes per node; lane covers 4 cols (8 B) of the 64-col H row
  int grp = l5 >> 4;
  int sub = l5 & 15;
  int c0b = sub << 3;           // byte offset of 4-col slice
  const char* Hb = (const char*)Hh;
  float4 a0 = f4s(0.f), a1 = f4s(0.f), a2 = f4s(0.f), a3 = f4s(0.f);  // per-head accumulators
  int nl = deg < GAT_CAP ? deg : GAT_CAP;
  int i = grp;
  for (; i + 2 < nl; i += 4){
    int o0 = sl[hw][i], o1 = sl[hw][i+2];
    float4 w0 = *(const float4*)&wl[hw][i<<2];
    float4 w1 = *(const float4*)&wl[hw][(i+2)<<2];
    uint2 u0 = *(const uint2*)(Hb + o0 + c0b);
    uint2 u1 = *(const uint2*)(Hb + o1 + c0b);
    float4 f0 = bfu2f4(u0);
    float4 f1 = bfu2f4(u1);
    a0 = f4fma(a0, w0.x, f0); a1 = f4fma(a1, w0.y, f0);
    a2 = f4fma(a2, w0.z, f0); a3 = f4fma(a3, w0.w, f0);
    a0 = f4fma(a0, w1.x, f1); a1 = f4fma(a1, w1.y, f1);
    a2 = f4fma(a2, w1.z, f1); a3 = f4fma(a3, w1.w, f1);
  }
  if (i < nl){
    float4 w0 = *(const float4*)&wl[hw][i<<2];
    float4 f0 = bfu2f4(*(const uint2*)(Hb + sl[hw][i] + c0b));
    a0 = f4fma(a0, w0.x, f0); a1 = f4fma(a1, w0.y, f0);
    a2 = f4fma(a2, w0.z, f0); a3 = f4fma(a3, w0.w, f0);
  }
  for (int j = nl + grp; j < deg; j += 2){   // LDS overflow fallback (essentially never)
    int s = csr[beg+j];
    float4 e = f4leaky(f4add(*(const float4*)(D + (size_t)s*8), ed));
    float4 w = f4expf(e);
    float4 f0 = bfu2f4(*(const uint2*)(Hb + ((size_t)s << 7) + c0b));
    a0 = f4fma(a0, w.x, f0); a1 = f4fma(a1, w.y, f0);
    a2 = f4fma(a2, w.z, f0); a3 = f4fma(a3, w.w, f0);
  }
  // cross-group reduce (lane stride 16, stays within half-wave)
  a0.x += __shfl_xor(a0.x, 16); a0.y += __shfl_xor(a0.y, 16); a0.z += __shfl_xor(a0.z, 16); a0.w += __shfl_xor(a0.w, 16);
  a1.x += __shfl_xor(a1.x, 16); a1.y += __shfl_xor(a1.y, 16); a1.z += __shfl_xor(a1.z, 16); a1.w += __shfl_xor(a1.w, 16);
  a2.x += __shfl_xor(a2.x, 16); a2.y += __shfl_xor(a2.y, 16); a2.z += __shfl_xor(a2.z, 16); a2.w += __shfl_xor(a2.w, 16);
  a3.x += __shfl_xor(a3.x, 16); a3.y += __shfl_xor(a3.y, 16); a3.z += __shfl_xor(a3.z, 16); a3.w += __shfl_xor(a3.w, 16);
  if (grp == 0){
    float4 fs = bfu2f4(*(const uint2*)(Hb + ((size_t)node << 7) + c0b));   // self term
    a0 = f4fma(a0, wself.x, fs);
    a1 = f4fma(a1, wself.y, fs);
    a2 = f4fma(a2, wself.z, fs);
    a3 = f4fma(a3, wself.w, fs);
    a0 = f4scale(a0, 1.f/(z4.x + 1e-16f));
    a1 = f4scale(a1, 1.f/(z4.y + 1e-16f));
    a2 = f4scale(a2, 1.f/(z4.z + 1e-16f));
    a3 = f4scale(a3, 1.f/(z4.w + 1e-16f));
    // Y layout: head-major [nd][h*64 + c]
    unsigned short* yp = Y + (size_t)node*256 + (sub << 2);
    *(ushort4*)(yp)       = f2bf4(a0);
    *(ushort4*)(yp + 64)  = f2bf4(a1);
    *(ushort4*)(yp + 128) = f2bf4(a2);
    *(ushort4*)(yp + 192) = f2bf4(a3);
  }
}

// ---------- SAGE aggregation: 4 nodes/wave, 16 lanes/node = 2 groups x 8 lanes; T = [P|R] ----------
__global__ __launch_bounds__(256) void k_sage(const unsigned short* __restrict__ T,
                                              const float* __restrict__ b, const int* __restrict__ offs,
                                              const int* __restrict__ csr, unsigned short* __restrict__ S, int n){
  int l = threadIdx.x & 63;
  int node = (((blockIdx.x*256 + threadIdx.x) >> 6) << 2) + (l >> 4);
  int l15 = l & 15;
  int grp = l15 >> 3, sub = l15 & 7;
  bool ok = node < n;
  int beg = 0, end = 0;
  if (ok){ beg = offs[node]; end = offs[node+1]; }
  float4 aL0 = f4s(0.f), aH0 = f4s(0.f), aL1 = f4s(0.f), aH1 = f4s(0.f);
  int i = beg + grp;
  for (; i + 2 < end; i += 4){
    int s0 = csr[i], s1 = csr[i+2];
    uint4 u0 = *(const uint4*)(T + (size_t)s0*128 + (sub<<3));
    uint4 u1 = *(const uint4*)(T + (size_t)s1*128 + (sub<<3));
    aL0 = f4add(aL0, bfu2f4_lo(u0)); aH0 = f4add(aH0, bfu2f4_hi(u0));
    aL1 = f4add(aL1, bfu2f4_lo(u1)); aH1 = f4add(aH1, bfu2f4_hi(u1));
  }
  if (i < end){
    int s0 = csr[i];
    uint4 u0 = *(const uint4*)(T + (size_t)s0*128 + (sub<<3));
    aL0 = f4add(aL0, bfu2f4_lo(u0)); aH0 = f4add(aH0, bfu2f4_hi(u0));
  }
  float4 aL = f4add(aL0, aL1), aH = f4add(aH0, aH1);
  red2(aL, aH);
  if (ok && grp == 0){
    float minv = 1.f / fmaxf((float)(end - beg), 1.f);
    uint4 ur = *(const uint4*)(T + (size_t)node*128 + 64 + (sub<<3));
    float4 b0 = *(const float4*)(b + (sub<<3));
    float4 b1 = *(const float4*)(b + (sub<<3) + 4);
    float4 r0 = f4relu(f4add(f4fma(b0, minv, aL), bfu2f4_lo(ur)));
    float4 r1 = f4relu(f4add(f4fma(b1, minv, aH), bfu2f4_hi(ur)));
    *(u16x8*)(S + (size_t)node*64 + (sub<<3)) = f2bf8(r0, r1);
  }
}

// ---------- edge MLP, edge-order: 8 lanes/edge, coalesced out writes ----------
__global__ __launch_bounds__(256) void k_mlp(const unsigned short* __restrict__ T2,
                                             const float* __restrict__ b1, const float* __restrict__ W2,
                                             const float* __restrict__ b2, const int* __restrict__ src,
                                             const int* __restrict__ dst, float* __restrict__ out, int E){
  int t = threadIdx.x;
  int e = blockIdx.x*32 + (t >> 3);
  if (e >= E) return;
  int sub = t & 7;
  int s = src[e], d = dst[e];
  uint4 u = *(const uint4*)(T2 + (size_t)s*128 + (sub<<3));        // U[s]
  uint4 v = *(const uint4*)(T2 + (size_t)d*128 + 64 + (sub<<3));   // V[d]
  float4 bb0 = *(const float4*)(b1 + (sub<<3));
  float4 bb1 = *(const float4*)(b1 + (sub<<3) + 4);
  float4 w0 = *(const float4*)(W2 + (sub<<3));
  float4 w1 = *(const float4*)(W2 + (sub<<3) + 4);
  float4 ta = f4relu(f4add(f4add(bfu2f4_lo(u), bfu2f4_lo(v)), bb0));
  float4 tb = f4relu(f4add(f4add(bfu2f4_hi(u), bfu2f4_hi(v)), bb1));
  float p = ta.x*w0.x + ta.y*w0.y + ta.z*w0.z + ta.w*w0.w
          + tb.x*w1.x + tb.y*w1.y + tb.z*w1.z + tb.w*w1.w;
  p += __shfl_xor(p, 1);
  p += __shfl_xor(p, 2);
  p += __shfl_xor(p, 4);
  if (sub == 0) out[e] = 1.f / (1.f + __expf(-(p + b2[0])));
}

extern "C" void kernel_launch(void* const* d_in, const int* in_sizes, int n_in,
                              void* d_out, int out_size, void* d_ws, size_t ws_size,
                              hipStream_t stream){
  const float* x     = (const float*)d_in[0];
  const int*   eidx  = (const int*)  d_in[1];
  const float* W_gcn = (const float*)d_in[2];
  const float* b_gcn = (const float*)d_in[3];
  const float* W_gat = (const float*)d_in[4];
  const float* att_s = (const float*)d_in[5];
  const float* att_d = (const float*)d_in[6];
  const float* b_gat = (const float*)d_in[7];
  const float* W_sl  = (const float*)d_in[8];
  const float* b_sg  = (const float*)d_in[9];
  const float* W_sr  = (const float*)d_in[10];
  const float* W1    = (const float*)d_in[11];
  const float* b1    = (const float*)d_in[12];
  const float* W2    = (const float*)d_in[13];
  const float* b2    = (const float*)d_in[14];
  float* out = (float*)d_out;

  const int N = in_sizes[0] / 128;
  const int E = in_sizes[1] / 2;
  const int* src = eidx;
  const int* dst = eidx + E;

  // ---- workspace layout: f32 first, then bf16, then int ----
  float* ws   = (float*)d_ws;
  float* dinv = ws;                        // N
  float* D    = dinv + (size_t)N;          // N*8  (a_s | a_d)
  float* Vs   = D + (size_t)N*8;           // 256
  float* Vd   = Vs + 256;                  // 256
  unsigned short* A0 = (unsigned short*)(Vd + 256);        // N*64  bf16 (dinv * x @ W_gcn)
  unsigned short* H  = A0 + (size_t)N*64;  // N*64  bf16 (GCN out)
  unsigned short* Y  = H  + (size_t)N*64;  // N*256 bf16 (per-head weighted H sums)
  unsigned short* G  = Y  + (size_t)N*256; // N*256 bf16 (GAT out)
  unsigned short* T  = G  + (size_t)N*256; // N*128 bf16 (P | R)
  unsigned short* S  = T  + (size_t)N*128; // N*64  bf16 (SAGE out)
  unsigned short* T2 = S  + (size_t)N*64;  // N*128 bf16 (U | V)
  int* cnt  = (int*)(T2 + (size_t)N*128);  // N
  int* excl = cnt + N;                     // N
  int* bsum = excl + N;                    // 256
  int* offs = bsum + 256;                  // N+1
  int* head = offs + N + 1;                // N
  int* csr  = head + N;                    // E

  const int nb = (N + 255) / 256;
  const int gtiles = (N + 63) / 64;
  const int nwb = (N + 15) / 16;          // 4 nodes/wave kernels: 16 nodes per 256-thread block

  // ---- CSR build + dinv + attention basis vectors ----
  hipMemsetAsync(cnt, 0, (size_t)N*sizeof(int), stream);
  k_count<<<(E+255)/256, 256, 0, stream>>>(dst, cnt, E);
  k_scan1<<<nb, 256, 0, stream>>>(cnt, excl, bsum, N);
  k_scan2v<<<1, 256, 0, stream>>>(bsum, nb, W_gat, att_s, att_d, Vs, Vd);
  k_scan3<<<nb, 256, 0, stream>>>(cnt, excl, bsum, offs, head, dinv, N, E);
  k_fill<<<(E+255)/256, 256, 0, stream>>>(src, dst, head, csr, E);

  // ---- GCN: A0 = bf16(dinv * (x @ W_gcn)); H = relu(...); D = GAT logits from H ----
  k_mgemm<128, 64, false, true, false, false, false><<<gtiles, 256, 128*64*2, stream>>>(
      x, 128, W_gcn, 64, nullptr, 0, A0, 64, N, dinv, nullptr);
  k_gcn <<<nwb, 256, 0, stream>>>(A0, dinv, b_gcn, offs, csr, H, N);
  k_asdh<<<(N*4+255)/256, 256, 0, stream>>>(H, Vs, Vd, D, N);

  // ---- GAT: softmax + H-domain aggregation -> Y; per-head GEMM + bias + relu -> G ----
  k_gat2<<<(N+7)/8, 256, 0, stream>>>(D, H, offs, csr, Y, N);
  k_mgemm<64, 256, true, false, false, true, true><<<gtiles, 256, 64*256*2, stream>>>(
      Y, 256, W_gat, 256, nullptr, 0, G, 256, N, nullptr, b_gat);

  // ---- SAGE: T = bf16(G @ [W_sl | W_sr]); S = relu(mean(P[src]) + b + R) ----
  k_mgemm<256, 128, true, false, true, false, false><<<gtiles, 256, 256*128*2, stream>>>(
      G, 256, W_sl, 64, W_sr, 64, T, 128, N, nullptr, nullptr);
  k_sage<<<nwb, 256, 0, stream>>>(T, b_sg, offs, csr, S, N);

  // ---- edge MLP: T2 = bf16(S @ [W1_top | W1_bot]); edge-order eval, coalesced out ----
  k_mgemm<64, 128, true, false, true, false, false><<<gtiles, 256, 64*128*2, stream>>>(
      S, 64, W1, 64, W1 + 64*64, 64, T2, 128, N, nullptr, nullptr);
  k_mlp <<<(E+31)/32, 256, 0, stream>>>(T2, b1, W2, b2, src, dst, out, E);
}

// Round 14
// 355.881 us; speedup vs baseline: 1.0871x; 1.0871x over previous
//
#include <hip/hip_runtime.h>
#include <math.h>

// ---------- float4 / bf16 helpers ----------
static __device__ __forceinline__ float4 f4s(float v){ return make_float4(v,v,v,v); }
static __device__ __forceinline__ float4 f4add(float4 a, float4 b){ return make_float4(a.x+b.x,a.y+b.y,a.z+b.z,a.w+b.w); }
static __device__ __forceinline__ float4 f4max(float4 a, float4 b){ return make_float4(fmaxf(a.x,b.x),fmaxf(a.y,b.y),fmaxf(a.z,b.z),fmaxf(a.w,b.w)); }
static __device__ __forceinline__ float4 f4scale(float4 a, float s){ return make_float4(a.x*s,a.y*s,a.z*s,a.w*s); }
static __device__ __forceinline__ float4 f4fma(float4 acc, float s, float4 b){
  acc.x += s*b.x; acc.y += s*b.y; acc.z += s*b.z; acc.w += s*b.w; return acc;
}
static __device__ __forceinline__ float4 f4relu(float4 a){ return f4max(a, f4s(0.f)); }
static __device__ __forceinline__ float4 f4leaky(float4 a){
  return make_float4(a.x>0.f?a.x:0.2f*a.x, a.y>0.f?a.y:0.2f*a.y, a.z>0.f?a.z:0.2f*a.z, a.w>0.f?a.w:0.2f*a.w);
}
static __device__ __forceinline__ float4 f4expf(float4 a){ return make_float4(__expf(a.x),__expf(a.y),__expf(a.z),__expf(a.w)); }
static __device__ __forceinline__ unsigned short f2bf(float f){
  unsigned int u = __float_as_uint(f);
  unsigned int r = (u + 0x7fffu + ((u >> 16) & 1u)) >> 16;
  return (unsigned short)r;
}
static __device__ __forceinline__ ushort4 f2bf4(float4 f){
  ushort4 r; r.x=f2bf(f.x); r.y=f2bf(f.y); r.z=f2bf(f.z); r.w=f2bf(f.w); return r;
}
// bf16x4 (as uint2) -> float4 : 4 VALU ops
static __device__ __forceinline__ float4 bfu2f4(uint2 u){
  return make_float4(__uint_as_float(u.x << 16), __uint_as_float(u.x & 0xffff0000u),
                     __uint_as_float(u.y << 16), __uint_as_float(u.y & 0xffff0000u));
}
static __device__ __forceinline__ float4 bfu2f4_lo(uint4 u){ return bfu2f4(make_uint2(u.x, u.y)); }
static __device__ __forceinline__ float4 bfu2f4_hi(uint4 u){ return bfu2f4(make_uint2(u.z, u.w)); }

typedef __attribute__((ext_vector_type(8))) unsigned short u16x8;
static __device__ __forceinline__ u16x8 f2bf8(float4 a, float4 b){
  u16x8 r;
  r[0]=f2bf(a.x); r[1]=f2bf(a.y); r[2]=f2bf(a.z); r[3]=f2bf(a.w);
  r[4]=f2bf(b.x); r[5]=f2bf(b.y); r[6]=f2bf(b.z); r[7]=f2bf(b.w);
  return r;
}
// reduce two float4 across 2 groups at lane stride 8
static __device__ __forceinline__ void red2(float4& a, float4& b){
  a.x += __shfl_xor(a.x, 8); a.y += __shfl_xor(a.y, 8);
  a.z += __shfl_xor(a.z, 8); a.w += __shfl_xor(a.w, 8);
  b.x += __shfl_xor(b.x, 8); b.y += __shfl_xor(b.y, 8);
  b.z += __shfl_xor(b.z, 8); b.w += __shfl_xor(b.w, 8);
}

// ---------- MFMA types ----------
typedef __attribute__((ext_vector_type(8))) short bf16x8;   // 8 bf16 = 4 VGPRs
typedef __attribute__((ext_vector_type(4))) float f32x4;

// ---------- CSR build ----------
// rank pass: per-edge within-dst rank via atomic; rank written coalesced.
__global__ __launch_bounds__(256) void k_rank(const int* __restrict__ dst, int* __restrict__ cnt,
                                              int* __restrict__ rank, int E){
  int t = blockIdx.x*256 + threadIdx.x;
  if (t < E) rank[t] = atomicAdd(&cnt[dst[t]], 1);
}
__global__ __launch_bounds__(256) void k_scan1(const int* __restrict__ cnt, int* __restrict__ excl,
                                               int* __restrict__ bsum, int n){
  __shared__ int sc[256];
  int t = threadIdx.x; int i = blockIdx.x*256 + t;
  int v = (i<n)?cnt[i]:0;
  sc[t]=v; __syncthreads();
  for (int o=1;o<256;o<<=1){ int a=(t>=o)?sc[t-o]:0; __syncthreads(); sc[t]+=a; __syncthreads(); }
  if (i<n) excl[i] = sc[t]-v;
  if (t==255) bsum[blockIdx.x] = sc[t];
}
// scan of block sums + (fused) GAT attention basis vectors Vs/Vd
__global__ __launch_bounds__(256) void k_scan2v(int* __restrict__ bsum, int nb,
                                                const float* __restrict__ Wg, const float* __restrict__ as,
                                                const float* __restrict__ ad, float* __restrict__ Vs,
                                                float* __restrict__ Vd){
  __shared__ int sc[256];
  int t = threadIdx.x;
  int v = (t<nb)?bsum[t]:0;
  sc[t]=v; __syncthreads();
  for (int o=1;o<256;o<<=1){ int a=(t>=o)?sc[t-o]:0; __syncthreads(); sc[t]+=a; __syncthreads(); }
  if (t<nb) bsum[t] = sc[t]-v;
  // Vs[h][k] = sum_c W_gat[k][h*64+c]*att_s[h][c]  (t = h*64+k)
  int h = t >> 6, k = t & 63;
  float s = 0.f, d = 0.f;
  const float* wr = Wg + (size_t)k*256 + h*64;
  const float* ar = as + h*64;
  const float* dr = ad + h*64;
  for (int c = 0; c < 64; ++c){ float w = wr[c]; s += w*ar[c]; d += w*dr[c]; }
  Vs[t] = s; Vd[t] = d;
}
__global__ __launch_bounds__(256) void k_scan3(const int* __restrict__ cnt, const int* __restrict__ excl,
                                               const int* __restrict__ bsum, int* __restrict__ offs,
                                               float* __restrict__ dinv, int n, int E){
  int i = blockIdx.x*256 + threadIdx.x;
  if (i < n){
    int o = excl[i] + bsum[blockIdx.x];
    offs[i] = o;
    dinv[i] = rsqrtf((float)cnt[i] + 1.0f);   // deg includes self-loop
    if (i == 0) offs[n] = E;
  }
}
// scatter-only fill: no atomic, store can fire-and-forget.
__global__ __launch_bounds__(256) void k_fill(const int* __restrict__ src, const int* __restrict__ dst,
                                              const int* __restrict__ offs, const int* __restrict__ rank,
                                              int* __restrict__ csr, int E){
  int t = blockIdx.x*256 + threadIdx.x;
  if (t < E) csr[offs[dst[t]] + rank[t]] = src[t];
}

// ---------- GAT logits from H: D[nd][h] = H[nd].Vs[h], D[nd][4+h] = H[nd].Vd[h] ----------
__global__ __launch_bounds__(256) void k_asdh(const unsigned short* __restrict__ Hh,
                                              const float* __restrict__ Vs, const float* __restrict__ Vd,
                                              float* __restrict__ D, int n){
  __shared__ float vs[256], vd[256];
  int t = threadIdx.x;
  vs[t] = Vs[t]; vd[t] = Vd[t];
  __syncthreads();
  int idx = blockIdx.x*256 + t;
  if (idx >= n*4) return;
  int nd = idx >> 2, h = idx & 3;
  const unsigned short* hr = Hh + (size_t)nd*64;
  const float* vsr = vs + h*64;
  const float* vdr = vd + h*64;
  float s = 0.f, d = 0.f;
  #pragma unroll
  for (int k = 0; k < 8; ++k){
    uint4 u = *(const uint4*)(hr + k*8);
    float4 lo = bfu2f4_lo(u), hi = bfu2f4_hi(u);
    const float* a = vsr + k*8;
    const float* b = vdr + k*8;
    s += lo.x*a[0]+lo.y*a[1]+lo.z*a[2]+lo.w*a[3] + hi.x*a[4]+hi.y*a[5]+hi.z*a[6]+hi.w*a[7];
    d += lo.x*b[0]+lo.y*b[1]+lo.z*b[2]+lo.w*b[3] + hi.x*b[4]+hi.y*b[5]+hi.z*b[6]+hi.w*b[7];
  }
  D[(size_t)nd*8 + h]     = s;
  D[(size_t)nd*8 + 4 + h] = d;
}

// ---------- MFMA GEMM: out[n,Cout](bf16) = in[n,K] @ W, W f32->bf16 staged in LDS ----------
template<int K, int Cout, bool IBF16, bool SCALE, bool DUAL, bool H4, bool BRELU>
__global__ __launch_bounds__(256) void k_mgemm(const void* __restrict__ in, int ldin,
                                               const float* __restrict__ Wa, int ldwa,
                                               const float* __restrict__ Wb, int ldwb,
                                               unsigned short* __restrict__ out, int ldout,
                                               int n, const float* __restrict__ rowscale,
                                               const float* __restrict__ bias){
  constexpr int CC = Cout >> 4;       // 16-col chunks
  constexpr int KB = K >> 5;          // 32-k blocks
  constexpr int NH = H4 ? 4 : 1;
  extern __shared__ unsigned short wb[];
  int tid = threadIdx.x;
  constexpr int nslots = KB*CC*64;
  for (int s = tid; s < nslots; s += 256){
    int l = s & 63;
    int f = s >> 6;                   // frag = kb*CC + cc
    int cc = f % CC, kb = f / CC;
    int c  = cc*16 + (l & 15);
    int kr = kb*32 + ((l >> 4) << 3);
    const float* wp; int ld;
    if (DUAL && c >= (Cout/2)){ wp = Wb + (size_t)kr*ldwb + (c - Cout/2); ld = ldwb; }
    else                      { wp = Wa + (size_t)kr*ldwa + c;            ld = ldwa; }
    unsigned short* dp = &wb[s*8];
    #pragma unroll
    for (int j = 0; j < 8; ++j) dp[j] = f2bf(wp[(size_t)j*ld]);
  }
  __syncthreads();
  int wv = tid >> 6, l = tid & 63;
  int lrow = l & 15;
  int lk = (l >> 4) << 3;
  int ngrp = (n + 63) >> 6;
  const unsigned short* inb = (const unsigned short*)in;
  const float* inf = (const float*)in;
  for (int g = blockIdx.x; g < ngrp; g += gridDim.x){
    int r0 = (g << 6) + (wv << 4);
    int m = r0 + lrow;
    bf16x8 afr[NH][KB];
    #pragma unroll
    for (int h = 0; h < NH; ++h){
      #pragma unroll
      for (int kb = 0; kb < KB; ++kb){
        bf16x8 a = {0,0,0,0,0,0,0,0};
        if (m < n){
          int off = (H4 ? h*64 : 0) + kb*32 + lk;
          if (IBF16){
            a = *(const bf16x8*)(inb + (size_t)m*ldin + off);
          } else {
            const float* p = inf + (size_t)m*ldin + off;
            float4 f0 = *(const float4*)p;
            float4 f1 = *(const float4*)(p + 4);
            a[0]=(short)f2bf(f0.x); a[1]=(short)f2bf(f0.y); a[2]=(short)f2bf(f0.z); a[3]=(short)f2bf(f0.w);
            a[4]=(short)f2bf(f1.x); a[5]=(short)f2bf(f1.y); a[6]=(short)f2bf(f1.z); a[7]=(short)f2bf(f1.w);
          }
        }
        afr[h][kb] = a;
      }
    }
    int rbase = r0 + ((l >> 4) << 2);
    float sc[4];
    if (SCALE){
      #pragma unroll
      for (int r = 0; r < 4; ++r) sc[r] = (rbase + r < n) ? rowscale[rbase + r] : 0.f;
    }
    #pragma unroll
    for (int cc = 0; cc < CC; ++cc){
      f32x4 acc = {0.f, 0.f, 0.f, 0.f};
      constexpr int hstep = H4 ? 1 : 0;
      int hh = hstep ? (cc >> 2) : 0;
      #pragma unroll
      for (int kb = 0; kb < KB; ++kb){
        bf16x8 b = *(const bf16x8*)&wb[((kb*CC + cc)*64 + l)*8];
        acc = __builtin_amdgcn_mfma_f32_16x16x32_bf16(afr[hh][kb], b, acc, 0, 0, 0);
      }
      int c = cc*16 + lrow;
      float bv = BRELU ? bias[c] : 0.f;
      #pragma unroll
      for (int r = 0; r < 4; ++r){
        int rr = rbase + r;
        if (rr < n){
          float v = acc[r];
          if (SCALE) v *= sc[r];
          if (BRELU) v = fmaxf(v + bv, 0.f);
          out[(size_t)rr*ldout + c] = f2bf(v);
        }
      }
    }
  }
}

// ---------- GCN aggregation: 4 nodes/wave, 16 lanes/node = 2 edge-groups x 8 lanes ----------
// A0 rows pre-scaled by dinv[src]; H = relu(dinv_d*(sum+self) + b), bf16 out.
__global__ __launch_bounds__(256) void k_gcn(const unsigned short* __restrict__ h0, const float* __restrict__ dinv,
                                             const float* __restrict__ b, const int* __restrict__ offs,
                                             const int* __restrict__ csr, unsigned short* __restrict__ h, int n){
  int l = threadIdx.x & 63;
  int node = (((blockIdx.x*256 + threadIdx.x) >> 6) << 2) + (l >> 4);
  int l15 = l & 15;
  int grp = l15 >> 3, sub = l15 & 7;
  bool ok = node < n;
  int beg = 0, end = 0;
  float di = 0.f;
  if (ok){ beg = offs[node]; end = offs[node+1]; di = dinv[node]; }
  float4 aL0 = f4s(0.f), aH0 = f4s(0.f), aL1 = f4s(0.f), aH1 = f4s(0.f);
  int i = beg + grp;
  for (; i + 2 < end; i += 4){
    int s0 = csr[i], s1 = csr[i+2];
    uint4 u0 = *(const uint4*)(h0 + (size_t)s0*64 + (sub<<3));
    uint4 u1 = *(const uint4*)(h0 + (size_t)s1*64 + (sub<<3));
    aL0 = f4add(aL0, bfu2f4_lo(u0)); aH0 = f4add(aH0, bfu2f4_hi(u0));
    aL1 = f4add(aL1, bfu2f4_lo(u1)); aH1 = f4add(aH1, bfu2f4_hi(u1));
  }
  if (i < end){
    int s0 = csr[i];
    uint4 u0 = *(const uint4*)(h0 + (size_t)s0*64 + (sub<<3));
    aL0 = f4add(aL0, bfu2f4_lo(u0)); aH0 = f4add(aH0, bfu2f4_hi(u0));
  }
  float4 aL = f4add(aL0, aL1), aH = f4add(aH0, aH1);
  red2(aL, aH);
  if (ok && grp == 0){
    uint4 us = *(const uint4*)(h0 + (size_t)node*64 + (sub<<3));   // self (pre-scaled)
    aL = f4add(aL, bfu2f4_lo(us)); aH = f4add(aH, bfu2f4_hi(us));
    float4 b0 = *(const float4*)(b + (sub<<3));
    float4 b1 = *(const float4*)(b + (sub<<3) + 4);
    float4 r0 = f4relu(f4fma(b0, di, aL));
    float4 r1 = f4relu(f4fma(b1, di, aH));
    *(u16x8*)(h + (size_t)node*64 + (sub<<3)) = f2bf8(r0, r1);
  }
}

// ---------- fused GAT softmax + H-domain aggregation: 2 nodes/wave ----------
// Half-wave (32 lanes) per node; phase C = 2 edge-groups x 16 lanes per node.
// Each edge's H row read ONCE (uint2/lane), FMA'd into 4 per-head accumulators.
// No max-shift: logits are O(+-3); softmax is shift-invariant.
#define GAT_CAP 128
__global__ __launch_bounds__(256) void k_gat2(const float* __restrict__ D, const unsigned short* __restrict__ Hh,
                                              const int* __restrict__ offs, const int* __restrict__ csr,
                                              unsigned short* __restrict__ Y, int n){
  __shared__ float wl[8][GAT_CAP*4];
  __shared__ int   sl[8][GAT_CAP];
  int hw = threadIdx.x >> 5;                 // half-wave index in block (0..7)
  int node = (blockIdx.x*256 + threadIdx.x) >> 5;
  int l5 = threadIdx.x & 31;
  if (node >= n) return;
  int beg = offs[node], end = offs[node+1];
  int deg = end - beg;
  float4 ed  = *(const float4*)(D + (size_t)node*8 + 4);
  float4 es0 = *(const float4*)(D + (size_t)node*8);
  float4 wself = f4expf(f4leaky(f4add(es0, ed)));
  // phase A: per-edge exp weights + src byte-offset -> LDS (first GAT_CAP), z accumulation (all)
  float4 z4 = f4s(0.f);
  for (int i = beg + l5; i < end; i += 32){
    int s = csr[i];
    float4 w = f4expf(f4leaky(f4add(*(const float4*)(D + (size_t)s*8), ed)));
    int li = i - beg;
    if (li < GAT_CAP){ *(float4*)&wl[hw][li<<2] = w; sl[hw][li] = s << 7; }  // 128 B per H row
    z4 = f4add(z4, w);
  }
  // 32-lane butterfly (stays within each half-wave)
  for (int m = 1; m < 32; m <<= 1){
    z4.x += __shfl_xor(z4.x, m); z4.y += __shfl_xor(z4.y, m);
    z4.z += __shfl_xor(z4.z, m); z4.w += __shfl_xor(z4.w, m);
  }
  z4 = f4add(z4, wself);
  // phase C: 2 edge-groups x 16 lanes per node; lane covers 4 cols (8 B) of the 64-col H row
  int grp = l5 >> 4;
  int sub = l5 & 15;
  int c0b = sub << 3;           // byte offset of 4-col slice
  const char* Hb = (const char*)Hh;
  float4 a0 = f4s(0.f), a1 = f4s(0.f), a2 = f4s(0.f), a3 = f4s(0.f);  // per-head accumulators
  int nl = deg < GAT_CAP ? deg : GAT_CAP;
  int i = grp;
  for (; i + 2 < nl; i += 4){
    int o0 = sl[hw][i], o1 = sl[hw][i+2];
    float4 w0 = *(const float4*)&wl[hw][i<<2];
    float4 w1 = *(const float4*)&wl[hw][(i+2)<<2];
    uint2 u0 = *(const uint2*)(Hb + o0 + c0b);
    uint2 u1 = *(const uint2*)(Hb + o1 + c0b);
    float4 f0 = bfu2f4(u0);
    float4 f1 = bfu2f4(u1);
    a0 = f4fma(a0, w0.x, f0); a1 = f4fma(a1, w0.y, f0);
    a2 = f4fma(a2, w0.z, f0); a3 = f4fma(a3, w0.w, f0);
    a0 = f4fma(a0, w1.x, f1); a1 = f4fma(a1, w1.y, f1);
    a2 = f4fma(a2, w1.z, f1); a3 = f4fma(a3, w1.w, f1);
  }
  if (i < nl){
    float4 w0 = *(const float4*)&wl[hw][i<<2];
    float4 f0 = bfu2f4(*(const uint2*)(Hb + sl[hw][i] + c0b));
    a0 = f4fma(a0, w0.x, f0); a1 = f4fma(a1, w0.y, f0);
    a2 = f4fma(a2, w0.z, f0); a3 = f4fma(a3, w0.w, f0);
  }
  for (int j = nl + grp; j < deg; j += 2){   // LDS overflow fallback (essentially never)
    int s = csr[beg+j];
    float4 e = f4leaky(f4add(*(const float4*)(D + (size_t)s*8), ed));
    float4 w = f4expf(e);
    float4 f0 = bfu2f4(*(const uint2*)(Hb + ((size_t)s << 7) + c0b));
    a0 = f4fma(a0, w.x, f0); a1 = f4fma(a1, w.y, f0);
    a2 = f4fma(a2, w.z, f0); a3 = f4fma(a3, w.w, f0);
  }
  // cross-group reduce (lane stride 16, stays within half-wave)
  a0.x += __shfl_xor(a0.x, 16); a0.y += __shfl_xor(a0.y, 16); a0.z += __shfl_xor(a0.z, 16); a0.w += __shfl_xor(a0.w, 16);
  a1.x += __shfl_xor(a1.x, 16); a1.y += __shfl_xor(a1.y, 16); a1.z += __shfl_xor(a1.z, 16); a1.w += __shfl_xor(a1.w, 16);
  a2.x += __shfl_xor(a2.x, 16); a2.y += __shfl_xor(a2.y, 16); a2.z += __shfl_xor(a2.z, 16); a2.w += __shfl_xor(a2.w, 16);
  a3.x += __shfl_xor(a3.x, 16); a3.y += __shfl_xor(a3.y, 16); a3.z += __shfl_xor(a3.z, 16); a3.w += __shfl_xor(a3.w, 16);
  if (grp == 0){
    float4 fs = bfu2f4(*(const uint2*)(Hb + ((size_t)node << 7) + c0b));   // self term
    a0 = f4fma(a0, wself.x, fs);
    a1 = f4fma(a1, wself.y, fs);
    a2 = f4fma(a2, wself.z, fs);
    a3 = f4fma(a3, wself.w, fs);
    a0 = f4scale(a0, 1.f/(z4.x + 1e-16f));
    a1 = f4scale(a1, 1.f/(z4.y + 1e-16f));
    a2 = f4scale(a2, 1.f/(z4.z + 1e-16f));
    a3 = f4scale(a3, 1.f/(z4.w + 1e-16f));
    // Y layout: head-major [nd][h*64 + c]
    unsigned short* yp = Y + (size_t)node*256 + (sub << 2);
    *(ushort4*)(yp)       = f2bf4(a0);
    *(ushort4*)(yp + 64)  = f2bf4(a1);
    *(ushort4*)(yp + 128) = f2bf4(a2);
    *(ushort4*)(yp + 192) = f2bf4(a3);
  }
}

// ---------- SAGE aggregation: 4 nodes/wave, 16 lanes/node = 2 groups x 8 lanes; T = [P|R] ----------
__global__ __launch_bounds__(256) void k_sage(const unsigned short* __restrict__ T,
                                              const float* __restrict__ b, const int* __restrict__ offs,
                                              const int* __restrict__ csr, unsigned short* __restrict__ S, int n){
  int l = threadIdx.x & 63;
  int node = (((blockIdx.x*256 + threadIdx.x) >> 6) << 2) + (l >> 4);
  int l15 = l & 15;
  int grp = l15 >> 3, sub = l15 & 7;
  bool ok = node < n;
  int beg = 0, end = 0;
  if (ok){ beg = offs[node]; end = offs[node+1]; }
  float4 aL0 = f4s(0.f), aH0 = f4s(0.f), aL1 = f4s(0.f), aH1 = f4s(0.f);
  int i = beg + grp;
  for (; i + 2 < end; i += 4){
    int s0 = csr[i], s1 = csr[i+2];
    uint4 u0 = *(const uint4*)(T + (size_t)s0*128 + (sub<<3));
    uint4 u1 = *(const uint4*)(T + (size_t)s1*128 + (sub<<3));
    aL0 = f4add(aL0, bfu2f4_lo(u0)); aH0 = f4add(aH0, bfu2f4_hi(u0));
    aL1 = f4add(aL1, bfu2f4_lo(u1)); aH1 = f4add(aH1, bfu2f4_hi(u1));
  }
  if (i < end){
    int s0 = csr[i];
    uint4 u0 = *(const uint4*)(T + (size_t)s0*128 + (sub<<3));
    aL0 = f4add(aL0, bfu2f4_lo(u0)); aH0 = f4add(aH0, bfu2f4_hi(u0));
  }
  float4 aL = f4add(aL0, aL1), aH = f4add(aH0, aH1);
  red2(aL, aH);
  if (ok && grp == 0){
    float minv = 1.f / fmaxf((float)(end - beg), 1.f);
    uint4 ur = *(const uint4*)(T + (size_t)node*128 + 64 + (sub<<3));
    float4 b0 = *(const float4*)(b + (sub<<3));
    float4 b1 = *(const float4*)(b + (sub<<3) + 4);
    float4 r0 = f4relu(f4add(f4fma(b0, minv, aL), bfu2f4_lo(ur)));
    float4 r1 = f4relu(f4add(f4fma(b1, minv, aH), bfu2f4_hi(ur)));
    *(u16x8*)(S + (size_t)node*64 + (sub<<3)) = f2bf8(r0, r1);
  }
}

// ---------- edge MLP, edge-order: 8 lanes/edge, coalesced out writes ----------
__global__ __launch_bounds__(256) void k_mlp(const unsigned short* __restrict__ T2,
                                             const float* __restrict__ b1, const float* __restrict__ W2,
                                             const float* __restrict__ b2, const int* __restrict__ src,
                                             const int* __restrict__ dst, float* __restrict__ out, int E){
  int t = threadIdx.x;
  int e = blockIdx.x*32 + (t >> 3);
  if (e >= E) return;
  int sub = t & 7;
  int s = src[e], d = dst[e];
  uint4 u = *(const uint4*)(T2 + (size_t)s*128 + (sub<<3));        // U[s]
  uint4 v = *(const uint4*)(T2 + (size_t)d*128 + 64 + (sub<<3));   // V[d]
  float4 bb0 = *(const float4*)(b1 + (sub<<3));
  float4 bb1 = *(const float4*)(b1 + (sub<<3) + 4);
  float4 w0 = *(const float4*)(W2 + (sub<<3));
  float4 w1 = *(const float4*)(W2 + (sub<<3) + 4);
  float4 ta = f4relu(f4add(f4add(bfu2f4_lo(u), bfu2f4_lo(v)), bb0));
  float4 tb = f4relu(f4add(f4add(bfu2f4_hi(u), bfu2f4_hi(v)), bb1));
  float p = ta.x*w0.x + ta.y*w0.y + ta.z*w0.z + ta.w*w0.w
          + tb.x*w1.x + tb.y*w1.y + tb.z*w1.z + tb.w*w1.w;
  p += __shfl_xor(p, 1);
  p += __shfl_xor(p, 2);
  p += __shfl_xor(p, 4);
  if (sub == 0) out[e] = 1.f / (1.f + __expf(-(p + b2[0])));
}

extern "C" void kernel_launch(void* const* d_in, const int* in_sizes, int n_in,
                              void* d_out, int out_size, void* d_ws, size_t ws_size,
                              hipStream_t stream){
  const float* x     = (const float*)d_in[0];
  const int*   eidx  = (const int*)  d_in[1];
  const float* W_gcn = (const float*)d_in[2];
  const float* b_gcn = (const float*)d_in[3];
  const float* W_gat = (const float*)d_in[4];
  const float* att_s = (const float*)d_in[5];
  const float* att_d = (const float*)d_in[6];
  const float* b_gat = (const float*)d_in[7];
  const float* W_sl  = (const float*)d_in[8];
  const float* b_sg  = (const float*)d_in[9];
  const float* W_sr  = (const float*)d_in[10];
  const float* W1    = (const float*)d_in[11];
  const float* b1    = (const float*)d_in[12];
  const float* W2    = (const float*)d_in[13];
  const float* b2    = (const float*)d_in[14];
  float* out = (float*)d_out;

  const int N = in_sizes[0] / 128;
  const int E = in_sizes[1] / 2;
  const int* src = eidx;
  const int* dst = eidx + E;

  // ---- workspace layout: f32 first, then bf16, then int ----
  float* ws   = (float*)d_ws;
  float* dinv = ws;                        // N
  float* D    = dinv + (size_t)N;          // N*8  (a_s | a_d)
  float* Vs   = D + (size_t)N*8;           // 256
  float* Vd   = Vs + 256;                  // 256
  unsigned short* A0 = (unsigned short*)(Vd + 256);        // N*64  bf16 (dinv * x @ W_gcn)
  unsigned short* H  = A0 + (size_t)N*64;  // N*64  bf16 (GCN out)
  unsigned short* Y  = H  + (size_t)N*64;  // N*256 bf16 (per-head weighted H sums)
  unsigned short* G  = Y  + (size_t)N*256; // N*256 bf16 (GAT out)
  unsigned short* T  = G  + (size_t)N*256; // N*128 bf16 (P | R)
  unsigned short* S  = T  + (size_t)N*128; // N*64  bf16 (SAGE out)
  unsigned short* T2 = S  + (size_t)N*64;  // N*128 bf16 (U | V)
  int* cnt  = (int*)(T2 + (size_t)N*128);  // N
  int* excl = cnt + N;                     // N
  int* bsum = excl + N;                    // 256
  int* offs = bsum + 256;                  // N+1
  int* rank = offs + N + 1;                // E
  int* csr  = rank + E;                    // E

  const int nb = (N + 255) / 256;
  const int gtiles = (N + 63) / 64;
  const int nwb = (N + 15) / 16;          // 4 nodes/wave kernels: 16 nodes per 256-thread block

  // ---- CSR build + dinv + attention basis vectors ----
  hipMemsetAsync(cnt, 0, (size_t)N*sizeof(int), stream);
  k_rank<<<(E+255)/256, 256, 0, stream>>>(dst, cnt, rank, E);
  k_scan1<<<nb, 256, 0, stream>>>(cnt, excl, bsum, N);
  k_scan2v<<<1, 256, 0, stream>>>(bsum, nb, W_gat, att_s, att_d, Vs, Vd);
  k_scan3<<<nb, 256, 0, stream>>>(cnt, excl, bsum, offs, dinv, N, E);
  k_fill<<<(E+255)/256, 256, 0, stream>>>(src, dst, offs, rank, csr, E);

  // ---- GCN: A0 = bf16(dinv * (x @ W_gcn)); H = relu(...); D = GAT logits from H ----
  k_mgemm<128, 64, false, true, false, false, false><<<gtiles, 256, 128*64*2, stream>>>(
      x, 128, W_gcn, 64, nullptr, 0, A0, 64, N, dinv, nullptr);
  k_gcn <<<nwb, 256, 0, stream>>>(A0, dinv, b_gcn, offs, csr, H, N);
  k_asdh<<<(N*4+255)/256, 256, 0, stream>>>(H, Vs, Vd, D, N);

  // ---- GAT: softmax + H-domain aggregation -> Y; per-head GEMM + bias + relu -> G ----
  k_gat2<<<(N+7)/8, 256, 0, stream>>>(D, H, offs, csr, Y, N);
  k_mgemm<64, 256, true, false, false, true, true><<<gtiles, 256, 64*256*2, stream>>>(
      Y, 256, W_gat, 256, nullptr, 0, G, 256, N, nullptr, b_gat);

  // ---- SAGE: T = bf16(G @ [W_sl | W_sr]); S = relu(mean(P[src]) + b + R) ----
  k_mgemm<256, 128, true, false, true, false, false><<<gtiles, 256, 256*128*2, stream>>>(
      G, 256, W_sl, 64, W_sr, 64, T, 128, N, nullptr, nullptr);
  k_sage<<<nwb, 256, 0, stream>>>(T, b_sg, offs, csr, S, N);

  // ---- edge MLP: T2 = bf16(S @ [W1_top | W1_bot]); edge-order eval, coalesced out ----
  k_mgemm<64, 128, true, false, true, false, false><<<gtiles, 256, 64*128*2, stream>>>(
      S, 64, W1, 64, W1 + 64*64, 64, T2, 128, N, nullptr, nullptr);
  k_mlp <<<(E+31)/32, 256, 0, stream>>>(T2, b1, W2, b2, src, dst, out, E);
}

// Round 15
// 338.657 us; speedup vs baseline: 1.1424x; 1.0509x over previous
//
#include <hip/hip_runtime.h>
#include <math.h>

// ---------- float4 / bf16 / fp8 helpers ----------
typedef float v2f __attribute__((ext_vector_type(2)));
static __device__ __forceinline__ float4 f4s(float v){ return make_float4(v,v,v,v); }
static __device__ __forceinline__ float4 f4add(float4 a, float4 b){ return make_float4(a.x+b.x,a.y+b.y,a.z+b.z,a.w+b.w); }
static __device__ __forceinline__ float4 f4max(float4 a, float4 b){ return make_float4(fmaxf(a.x,b.x),fmaxf(a.y,b.y),fmaxf(a.z,b.z),fmaxf(a.w,b.w)); }
static __device__ __forceinline__ float4 f4scale(float4 a, float s){ return make_float4(a.x*s,a.y*s,a.z*s,a.w*s); }
static __device__ __forceinline__ float4 f4fma(float4 acc, float s, float4 b){
  acc.x += s*b.x; acc.y += s*b.y; acc.z += s*b.z; acc.w += s*b.w; return acc;
}
static __device__ __forceinline__ float4 f4relu(float4 a){ return f4max(a, f4s(0.f)); }
static __device__ __forceinline__ float4 f4leaky(float4 a){
  return make_float4(a.x>0.f?a.x:0.2f*a.x, a.y>0.f?a.y:0.2f*a.y, a.z>0.f?a.z:0.2f*a.z, a.w>0.f?a.w:0.2f*a.w);
}
static __device__ __forceinline__ float4 f4expf(float4 a){ return make_float4(__expf(a.x),__expf(a.y),__expf(a.z),__expf(a.w)); }
static __device__ __forceinline__ unsigned short f2bf(float f){
  unsigned int u = __float_as_uint(f);
  unsigned int r = (u + 0x7fffu + ((u >> 16) & 1u)) >> 16;
  return (unsigned short)r;
}
static __device__ __forceinline__ ushort4 f2bf4(float4 f){
  ushort4 r; r.x=f2bf(f.x); r.y=f2bf(f.y); r.z=f2bf(f.z); r.w=f2bf(f.w); return r;
}
// bf16x4 (as uint2) -> float4 : 4 VALU ops
static __device__ __forceinline__ float4 bfu2f4(uint2 u){
  return make_float4(__uint_as_float(u.x << 16), __uint_as_float(u.x & 0xffff0000u),
                     __uint_as_float(u.y << 16), __uint_as_float(u.y & 0xffff0000u));
}
static __device__ __forceinline__ float4 bfu2f4_lo(uint4 u){ return bfu2f4(make_uint2(u.x, u.y)); }
static __device__ __forceinline__ float4 bfu2f4_hi(uint4 u){ return bfu2f4(make_uint2(u.z, u.w)); }

typedef __attribute__((ext_vector_type(8))) unsigned short u16x8;
static __device__ __forceinline__ u16x8 f2bf8(float4 a, float4 b){
  u16x8 r;
  r[0]=f2bf(a.x); r[1]=f2bf(a.y); r[2]=f2bf(a.z); r[3]=f2bf(a.w);
  r[4]=f2bf(b.x); r[5]=f2bf(b.y); r[6]=f2bf(b.z); r[7]=f2bf(b.w);
  return r;
}
// reduce two float4 across 2 groups at lane stride 8
static __device__ __forceinline__ void red2(float4& a, float4& b){
  a.x += __shfl_xor(a.x, 8); a.y += __shfl_xor(a.y, 8);
  a.z += __shfl_xor(a.z, 8); a.w += __shfl_xor(a.w, 8);
  b.x += __shfl_xor(b.x, 8); b.y += __shfl_xor(b.y, 8);
  b.z += __shfl_xor(b.z, 8); b.w += __shfl_xor(b.w, 8);
}
static __device__ __forceinline__ unsigned char f2fp8(float v){
  return (unsigned char)(__builtin_amdgcn_cvt_pk_fp8_f32(v, v, 0, false) & 0xff);
}

// ---------- MFMA types ----------
typedef __attribute__((ext_vector_type(8))) short bf16x8;   // 8 bf16 = 4 VGPRs
typedef __attribute__((ext_vector_type(4))) float f32x4;

// ---------- CSR build ----------
// rank pass: per-edge within-dst rank via atomic; rank written coalesced.
__global__ __launch_bounds__(256) void k_rank(const int* __restrict__ dst, int* __restrict__ cnt,
                                              int* __restrict__ rank, int E){
  int t = blockIdx.x*256 + threadIdx.x;
  if (t < E) rank[t] = atomicAdd(&cnt[dst[t]], 1);
}
__global__ __launch_bounds__(256) void k_scan1(const int* __restrict__ cnt, int* __restrict__ excl,
                                               int* __restrict__ bsum, int n){
  __shared__ int sc[256];
  int t = threadIdx.x; int i = blockIdx.x*256 + t;
  int v = (i<n)?cnt[i]:0;
  sc[t]=v; __syncthreads();
  for (int o=1;o<256;o<<=1){ int a=(t>=o)?sc[t-o]:0; __syncthreads(); sc[t]+=a; __syncthreads(); }
  if (i<n) excl[i] = sc[t]-v;
  if (t==255) bsum[blockIdx.x] = sc[t];
}
// scan of block sums + (fused) GAT attention basis vectors Vs/Vd
__global__ __launch_bounds__(256) void k_scan2v(int* __restrict__ bsum, int nb,
                                                const float* __restrict__ Wg, const float* __restrict__ as,
                                                const float* __restrict__ ad, float* __restrict__ Vs,
                                                float* __restrict__ Vd){
  __shared__ int sc[256];
  int t = threadIdx.x;
  int v = (t<nb)?bsum[t]:0;
  sc[t]=v; __syncthreads();
  for (int o=1;o<256;o<<=1){ int a=(t>=o)?sc[t-o]:0; __syncthreads(); sc[t]+=a; __syncthreads(); }
  if (t<nb) bsum[t] = sc[t]-v;
  // Vs[h][k] = sum_c W_gat[k][h*64+c]*att_s[h][c]  (t = h*64+k)
  int h = t >> 6, k = t & 63;
  float s = 0.f, d = 0.f;
  const float* wr = Wg + (size_t)k*256 + h*64;
  const float* ar = as + h*64;
  const float* dr = ad + h*64;
  for (int c = 0; c < 64; ++c){ float w = wr[c]; s += w*ar[c]; d += w*dr[c]; }
  Vs[t] = s; Vd[t] = d;
}
__global__ __launch_bounds__(256) void k_scan3(const int* __restrict__ cnt, const int* __restrict__ excl,
                                               const int* __restrict__ bsum, int* __restrict__ offs,
                                               float* __restrict__ dinv, int n, int E){
  int i = blockIdx.x*256 + threadIdx.x;
  if (i < n){
    int o = excl[i] + bsum[blockIdx.x];
    offs[i] = o;
    dinv[i] = rsqrtf((float)cnt[i] + 1.0f);   // deg includes self-loop
    if (i == 0) offs[n] = E;
  }
}
// scatter-only fill: no atomic, store can fire-and-forget.
__global__ __launch_bounds__(256) void k_fill(const int* __restrict__ src, const int* __restrict__ dst,
                                              const int* __restrict__ offs, const int* __restrict__ rank,
                                              int* __restrict__ csr, int E){
  int t = blockIdx.x*256 + threadIdx.x;
  if (t < E) csr[offs[dst[t]] + rank[t]] = src[t];
}

// ---------- GAT logits from H: D[nd][h] = H[nd].Vs[h], D[nd][4+h] = H[nd].Vd[h] ----------
__global__ __launch_bounds__(256) void k_asdh(const unsigned short* __restrict__ Hh,
                                              const float* __restrict__ Vs, const float* __restrict__ Vd,
                                              float* __restrict__ D, int n){
  __shared__ float vs[256], vd[256];
  int t = threadIdx.x;
  vs[t] = Vs[t]; vd[t] = Vd[t];
  __syncthreads();
  int idx = blockIdx.x*256 + t;
  if (idx >= n*4) return;
  int nd = idx >> 2, h = idx & 3;
  const unsigned short* hr = Hh + (size_t)nd*64;
  const float* vsr = vs + h*64;
  const float* vdr = vd + h*64;
  float s = 0.f, d = 0.f;
  #pragma unroll
  for (int k = 0; k < 8; ++k){
    uint4 u = *(const uint4*)(hr + k*8);
    float4 lo = bfu2f4_lo(u), hi = bfu2f4_hi(u);
    const float* a = vsr + k*8;
    const float* b = vdr + k*8;
    s += lo.x*a[0]+lo.y*a[1]+lo.z*a[2]+lo.w*a[3] + hi.x*a[4]+hi.y*a[5]+hi.z*a[6]+hi.w*a[7];
    d += lo.x*b[0]+lo.y*b[1]+lo.z*b[2]+lo.w*b[3] + hi.x*b[4]+hi.y*b[5]+hi.z*b[6]+hi.w*b[7];
  }
  D[(size_t)nd*8 + h]     = s;
  D[(size_t)nd*8 + 4 + h] = d;
}

// ---------- MFMA GEMM: out[n,Cout] = in[n,K] @ W, W f32->bf16 staged in LDS ----------
// OFP8: output OCP e4m3 bytes; else bf16.
template<int K, int Cout, bool IBF16, bool SCALE, bool DUAL, bool H4, bool BRELU, bool OFP8>
__global__ __launch_bounds__(256) void k_mgemm(const void* __restrict__ in, int ldin,
                                               const float* __restrict__ Wa, int ldwa,
                                               const float* __restrict__ Wb, int ldwb,
                                               void* __restrict__ out, int ldout,
                                               int n, const float* __restrict__ rowscale,
                                               const float* __restrict__ bias){
  constexpr int CC = Cout >> 4;       // 16-col chunks
  constexpr int KB = K >> 5;          // 32-k blocks
  constexpr int NH = H4 ? 4 : 1;
  extern __shared__ unsigned short wb[];
  int tid = threadIdx.x;
  constexpr int nslots = KB*CC*64;
  for (int s = tid; s < nslots; s += 256){
    int l = s & 63;
    int f = s >> 6;                   // frag = kb*CC + cc
    int cc = f % CC, kb = f / CC;
    int c  = cc*16 + (l & 15);
    int kr = kb*32 + ((l >> 4) << 3);
    const float* wp; int ld;
    if (DUAL && c >= (Cout/2)){ wp = Wb + (size_t)kr*ldwb + (c - Cout/2); ld = ldwb; }
    else                      { wp = Wa + (size_t)kr*ldwa + c;            ld = ldwa; }
    unsigned short* dp = &wb[s*8];
    #pragma unroll
    for (int j = 0; j < 8; ++j) dp[j] = f2bf(wp[(size_t)j*ld]);
  }
  __syncthreads();
  int wv = tid >> 6, l = tid & 63;
  int lrow = l & 15;
  int lk = (l >> 4) << 3;
  int ngrp = (n + 63) >> 6;
  const unsigned short* inb = (const unsigned short*)in;
  const float* inf = (const float*)in;
  for (int g = blockIdx.x; g < ngrp; g += gridDim.x){
    int r0 = (g << 6) + (wv << 4);
    int m = r0 + lrow;
    bf16x8 afr[NH][KB];
    #pragma unroll
    for (int h = 0; h < NH; ++h){
      #pragma unroll
      for (int kb = 0; kb < KB; ++kb){
        bf16x8 a = {0,0,0,0,0,0,0,0};
        if (m < n){
          int off = (H4 ? h*64 : 0) + kb*32 + lk;
          if (IBF16){
            a = *(const bf16x8*)(inb + (size_t)m*ldin + off);
          } else {
            const float* p = inf + (size_t)m*ldin + off;
            float4 f0 = *(const float4*)p;
            float4 f1 = *(const float4*)(p + 4);
            a[0]=(short)f2bf(f0.x); a[1]=(short)f2bf(f0.y); a[2]=(short)f2bf(f0.z); a[3]=(short)f2bf(f0.w);
            a[4]=(short)f2bf(f1.x); a[5]=(short)f2bf(f1.y); a[6]=(short)f2bf(f1.z); a[7]=(short)f2bf(f1.w);
          }
        }
        afr[h][kb] = a;
      }
    }
    int rbase = r0 + ((l >> 4) << 2);
    float sc[4];
    if (SCALE){
      #pragma unroll
      for (int r = 0; r < 4; ++r) sc[r] = (rbase + r < n) ? rowscale[rbase + r] : 0.f;
    }
    #pragma unroll
    for (int cc = 0; cc < CC; ++cc){
      f32x4 acc = {0.f, 0.f, 0.f, 0.f};
      constexpr int hstep = H4 ? 1 : 0;
      int hh = hstep ? (cc >> 2) : 0;
      #pragma unroll
      for (int kb = 0; kb < KB; ++kb){
        bf16x8 b = *(const bf16x8*)&wb[((kb*CC + cc)*64 + l)*8];
        acc = __builtin_amdgcn_mfma_f32_16x16x32_bf16(afr[hh][kb], b, acc, 0, 0, 0);
      }
      int c = cc*16 + lrow;
      float bv = BRELU ? bias[c] : 0.f;
      #pragma unroll
      for (int r = 0; r < 4; ++r){
        int rr = rbase + r;
        if (rr < n){
          float v = acc[r];
          if (SCALE) v *= sc[r];
          if (BRELU) v = fmaxf(v + bv, 0.f);
          if (OFP8) ((unsigned char*)out)[(size_t)rr*ldout + c] = f2fp8(v);
          else      ((unsigned short*)out)[(size_t)rr*ldout + c] = f2bf(v);
        }
      }
    }
  }
}

// ---------- GCN aggregation: 4 nodes/wave, 16 lanes/node = 2 edge-groups x 8 lanes ----------
// A0 rows pre-scaled by dinv[src]; H = relu(dinv_d*(sum+self) + b), bf16 out.
__global__ __launch_bounds__(256) void k_gcn(const unsigned short* __restrict__ h0, const float* __restrict__ dinv,
                                             const float* __restrict__ b, const int* __restrict__ offs,
                                             const int* __restrict__ csr, unsigned short* __restrict__ h, int n){
  int l = threadIdx.x & 63;
  int node = (((blockIdx.x*256 + threadIdx.x) >> 6) << 2) + (l >> 4);
  int l15 = l & 15;
  int grp = l15 >> 3, sub = l15 & 7;
  bool ok = node < n;
  int beg = 0, end = 0;
  float di = 0.f;
  if (ok){ beg = offs[node]; end = offs[node+1]; di = dinv[node]; }
  float4 aL0 = f4s(0.f), aH0 = f4s(0.f), aL1 = f4s(0.f), aH1 = f4s(0.f);
  int i = beg + grp;
  for (; i + 2 < end; i += 4){
    int s0 = csr[i], s1 = csr[i+2];
    uint4 u0 = *(const uint4*)(h0 + (size_t)s0*64 + (sub<<3));
    uint4 u1 = *(const uint4*)(h0 + (size_t)s1*64 + (sub<<3));
    aL0 = f4add(aL0, bfu2f4_lo(u0)); aH0 = f4add(aH0, bfu2f4_hi(u0));
    aL1 = f4add(aL1, bfu2f4_lo(u1)); aH1 = f4add(aH1, bfu2f4_hi(u1));
  }
  if (i < end){
    int s0 = csr[i];
    uint4 u0 = *(const uint4*)(h0 + (size_t)s0*64 + (sub<<3));
    aL0 = f4add(aL0, bfu2f4_lo(u0)); aH0 = f4add(aH0, bfu2f4_hi(u0));
  }
  float4 aL = f4add(aL0, aL1), aH = f4add(aH0, aH1);
  red2(aL, aH);
  if (ok && grp == 0){
    uint4 us = *(const uint4*)(h0 + (size_t)node*64 + (sub<<3));   // self (pre-scaled)
    aL = f4add(aL, bfu2f4_lo(us)); aH = f4add(aH, bfu2f4_hi(us));
    float4 b0 = *(const float4*)(b + (sub<<3));
    float4 b1 = *(const float4*)(b + (sub<<3) + 4);
    float4 r0 = f4relu(f4fma(b0, di, aL));
    float4 r1 = f4relu(f4fma(b1, di, aH));
    *(u16x8*)(h + (size_t)node*64 + (sub<<3)) = f2bf8(r0, r1);
  }
}

// ---------- fused GAT softmax + H-domain aggregation: 2 nodes/wave ----------
#define GAT_CAP 128
__global__ __launch_bounds__(256) void k_gat2(const float* __restrict__ D, const unsigned short* __restrict__ Hh,
                                              const int* __restrict__ offs, const int* __restrict__ csr,
                                              unsigned short* __restrict__ Y, int n){
  __shared__ float wl[8][GAT_CAP*4];
  __shared__ int   sl[8][GAT_CAP];
  int hw = threadIdx.x >> 5;                 // half-wave index in block (0..7)
  int node = (blockIdx.x*256 + threadIdx.x) >> 5;
  int l5 = threadIdx.x & 31;
  if (node >= n) return;
  int beg = offs[node], end = offs[node+1];
  int deg = end - beg;
  float4 ed  = *(const float4*)(D + (size_t)node*8 + 4);
  float4 es0 = *(const float4*)(D + (size_t)node*8);
  float4 wself = f4expf(f4leaky(f4add(es0, ed)));
  // phase A: per-edge exp weights + src byte-offset -> LDS (first GAT_CAP), z accumulation (all)
  float4 z4 = f4s(0.f);
  for (int i = beg + l5; i < end; i += 32){
    int s = csr[i];
    float4 w = f4expf(f4leaky(f4add(*(const float4*)(D + (size_t)s*8), ed)));
    int li = i - beg;
    if (li < GAT_CAP){ *(float4*)&wl[hw][li<<2] = w; sl[hw][li] = s << 7; }  // 128 B per H row
    z4 = f4add(z4, w);
  }
  // 32-lane butterfly (stays within each half-wave)
  for (int m = 1; m < 32; m <<= 1){
    z4.x += __shfl_xor(z4.x, m); z4.y += __shfl_xor(z4.y, m);
    z4.z += __shfl_xor(z4.z, m); z4.w += __shfl_xor(z4.w, m);
  }
  z4 = f4add(z4, wself);
  // phase C: 2 edge-groups x 16 lanes per node; lane covers 4 cols (8 B) of the 64-col H row
  int grp = l5 >> 4;
  int sub = l5 & 15;
  int c0b = sub << 3;           // byte offset of 4-col slice
  const char* Hb = (const char*)Hh;
  float4 a0 = f4s(0.f), a1 = f4s(0.f), a2 = f4s(0.f), a3 = f4s(0.f);  // per-head accumulators
  int nl = deg < GAT_CAP ? deg : GAT_CAP;
  int i = grp;
  for (; i + 2 < nl; i += 4){
    int o0 = sl[hw][i], o1 = sl[hw][i+2];
    float4 w0 = *(const float4*)&wl[hw][i<<2];
    float4 w1 = *(const float4*)&wl[hw][(i+2)<<2];
    uint2 u0 = *(const uint2*)(Hb + o0 + c0b);
    uint2 u1 = *(const uint2*)(Hb + o1 + c0b);
    float4 f0 = bfu2f4(u0);
    float4 f1 = bfu2f4(u1);
    a0 = f4fma(a0, w0.x, f0); a1 = f4fma(a1, w0.y, f0);
    a2 = f4fma(a2, w0.z, f0); a3 = f4fma(a3, w0.w, f0);
    a0 = f4fma(a0, w1.x, f1); a1 = f4fma(a1, w1.y, f1);
    a2 = f4fma(a2, w1.z, f1); a3 = f4fma(a3, w1.w, f1);
  }
  if (i < nl){
    float4 w0 = *(const float4*)&wl[hw][i<<2];
    float4 f0 = bfu2f4(*(const uint2*)(Hb + sl[hw][i] + c0b));
    a0 = f4fma(a0, w0.x, f0); a1 = f4fma(a1, w0.y, f0);
    a2 = f4fma(a2, w0.z, f0); a3 = f4fma(a3, w0.w, f0);
  }
  for (int j = nl + grp; j < deg; j += 2){   // LDS overflow fallback (essentially never)
    int s = csr[beg+j];
    float4 e = f4leaky(f4add(*(const float4*)(D + (size_t)s*8), ed));
    float4 w = f4expf(e);
    float4 f0 = bfu2f4(*(const uint2*)(Hb + ((size_t)s << 7) + c0b));
    a0 = f4fma(a0, w.x, f0); a1 = f4fma(a1, w.y, f0);
    a2 = f4fma(a2, w.z, f0); a3 = f4fma(a3, w.w, f0);
  }
  // cross-group reduce (lane stride 16, stays within half-wave)
  a0.x += __shfl_xor(a0.x, 16); a0.y += __shfl_xor(a0.y, 16); a0.z += __shfl_xor(a0.z, 16); a0.w += __shfl_xor(a0.w, 16);
  a1.x += __shfl_xor(a1.x, 16); a1.y += __shfl_xor(a1.y, 16); a1.z += __shfl_xor(a1.z, 16); a1.w += __shfl_xor(a1.w, 16);
  a2.x += __shfl_xor(a2.x, 16); a2.y += __shfl_xor(a2.y, 16); a2.z += __shfl_xor(a2.z, 16); a2.w += __shfl_xor(a2.w, 16);
  a3.x += __shfl_xor(a3.x, 16); a3.y += __shfl_xor(a3.y, 16); a3.z += __shfl_xor(a3.z, 16); a3.w += __shfl_xor(a3.w, 16);
  if (grp == 0){
    float4 fs = bfu2f4(*(const uint2*)(Hb + ((size_t)node << 7) + c0b));   // self term
    a0 = f4fma(a0, wself.x, fs);
    a1 = f4fma(a1, wself.y, fs);
    a2 = f4fma(a2, wself.z, fs);
    a3 = f4fma(a3, wself.w, fs);
    a0 = f4scale(a0, 1.f/(z4.x + 1e-16f));
    a1 = f4scale(a1, 1.f/(z4.y + 1e-16f));
    a2 = f4scale(a2, 1.f/(z4.z + 1e-16f));
    a3 = f4scale(a3, 1.f/(z4.w + 1e-16f));
    // Y layout: head-major [nd][h*64 + c]
    unsigned short* yp = Y + (size_t)node*256 + (sub << 2);
    *(ushort4*)(yp)       = f2bf4(a0);
    *(ushort4*)(yp + 64)  = f2bf4(a1);
    *(ushort4*)(yp + 128) = f2bf4(a2);
    *(ushort4*)(yp + 192) = f2bf4(a3);
  }
}

// ---------- SAGE aggregation: 4 nodes/wave, 16 lanes/node = 2 groups x 8 lanes; T = [P|R] ----------
__global__ __launch_bounds__(256) void k_sage(const unsigned short* __restrict__ T,
                                              const float* __restrict__ b, const int* __restrict__ offs,
                                              const int* __restrict__ csr, unsigned short* __restrict__ S, int n){
  int l = threadIdx.x & 63;
  int node = (((blockIdx.x*256 + threadIdx.x) >> 6) << 2) + (l >> 4);
  int l15 = l & 15;
  int grp = l15 >> 3, sub = l15 & 7;
  bool ok = node < n;
  int beg = 0, end = 0;
  if (ok){ beg = offs[node]; end = offs[node+1]; }
  float4 aL0 = f4s(0.f), aH0 = f4s(0.f), aL1 = f4s(0.f), aH1 = f4s(0.f);
  int i = beg + grp;
  for (; i + 2 < end; i += 4){
    int s0 = csr[i], s1 = csr[i+2];
    uint4 u0 = *(const uint4*)(T + (size_t)s0*128 + (sub<<3));
    uint4 u1 = *(const uint4*)(T + (size_t)s1*128 + (sub<<3));
    aL0 = f4add(aL0, bfu2f4_lo(u0)); aH0 = f4add(aH0, bfu2f4_hi(u0));
    aL1 = f4add(aL1, bfu2f4_lo(u1)); aH1 = f4add(aH1, bfu2f4_hi(u1));
  }
  if (i < end){
    int s0 = csr[i];
    uint4 u0 = *(const uint4*)(T + (size_t)s0*128 + (sub<<3));
    aL0 = f4add(aL0, bfu2f4_lo(u0)); aH0 = f4add(aH0, bfu2f4_hi(u0));
  }
  float4 aL = f4add(aL0, aL1), aH = f4add(aH0, aH1);
  red2(aL, aH);
  if (ok && grp == 0){
    float minv = 1.f / fmaxf((float)(end - beg), 1.f);
    uint4 ur = *(const uint4*)(T + (size_t)node*128 + 64 + (sub<<3));
    float4 b0 = *(const float4*)(b + (sub<<3));
    float4 b1 = *(const float4*)(b + (sub<<3) + 4);
    float4 r0 = f4relu(f4add(f4fma(b0, minv, aL), bfu2f4_lo(ur)));
    float4 r1 = f4relu(f4add(f4fma(b1, minv, aH), bfu2f4_hi(ur)));
    *(u16x8*)(S + (size_t)node*64 + (sub<<3)) = f2bf8(r0, r1);
  }
}

// ---------- edge MLP, edge-order: 8 lanes/edge; T2 = [U|V] fp8 rows of 128 B ----------
__global__ __launch_bounds__(256) void k_mlp(const unsigned char* __restrict__ T2,
                                             const float* __restrict__ b1, const float* __restrict__ W2,
                                             const float* __restrict__ b2, const int* __restrict__ src,
                                             const int* __restrict__ dst, float* __restrict__ out, int E){
  int t = threadIdx.x;
  int e = blockIdx.x*32 + (t >> 3);
  if (e >= E) return;
  int sub = t & 7;
  int s = src[e], d = dst[e];
  uint2 uu = *(const uint2*)(T2 + (size_t)s*128 + (sub<<3));        // 8 fp8 of U[s]
  uint2 vv = *(const uint2*)(T2 + (size_t)d*128 + 64 + (sub<<3));   // 8 fp8 of V[d]
  v2f u0 = __builtin_amdgcn_cvt_pk_f32_fp8(uu.x, false);
  v2f u1 = __builtin_amdgcn_cvt_pk_f32_fp8(uu.x, true);
  v2f u2 = __builtin_amdgcn_cvt_pk_f32_fp8(uu.y, false);
  v2f u3 = __builtin_amdgcn_cvt_pk_f32_fp8(uu.y, true);
  v2f v0 = __builtin_amdgcn_cvt_pk_f32_fp8(vv.x, false);
  v2f v1 = __builtin_amdgcn_cvt_pk_f32_fp8(vv.x, true);
  v2f v2 = __builtin_amdgcn_cvt_pk_f32_fp8(vv.y, false);
  v2f v3 = __builtin_amdgcn_cvt_pk_f32_fp8(vv.y, true);
  float4 bb0 = *(const float4*)(b1 + (sub<<3));
  float4 bb1 = *(const float4*)(b1 + (sub<<3) + 4);
  float4 w0 = *(const float4*)(W2 + (sub<<3));
  float4 w1 = *(const float4*)(W2 + (sub<<3) + 4);
  float p = fmaxf(u0[0]+v0[0]+bb0.x, 0.f)*w0.x
          + fmaxf(u0[1]+v0[1]+bb0.y, 0.f)*w0.y
          + fmaxf(u1[0]+v1[0]+bb0.z, 0.f)*w0.z
          + fmaxf(u1[1]+v1[1]+bb0.w, 0.f)*w0.w
          + fmaxf(u2[0]+v2[0]+bb1.x, 0.f)*w1.x
          + fmaxf(u2[1]+v2[1]+bb1.y, 0.f)*w1.y
          + fmaxf(u3[0]+v3[0]+bb1.z, 0.f)*w1.z
          + fmaxf(u3[1]+v3[1]+bb1.w, 0.f)*w1.w;
  p += __shfl_xor(p, 1);
  p += __shfl_xor(p, 2);
  p += __shfl_xor(p, 4);
  if (sub == 0) out[e] = 1.f / (1.f + __expf(-(p + b2[0])));
}

extern "C" void kernel_launch(void* const* d_in, const int* in_sizes, int n_in,
                              void* d_out, int out_size, void* d_ws, size_t ws_size,
                              hipStream_t stream){
  const float* x     = (const float*)d_in[0];
  const int*   eidx  = (const int*)  d_in[1];
  const float* W_gcn = (const float*)d_in[2];
  const float* b_gcn = (const float*)d_in[3];
  const float* W_gat = (const float*)d_in[4];
  const float* att_s = (const float*)d_in[5];
  const float* att_d = (const float*)d_in[6];
  const float* b_gat = (const float*)d_in[7];
  const float* W_sl  = (const float*)d_in[8];
  const float* b_sg  = (const float*)d_in[9];
  const float* W_sr  = (const float*)d_in[10];
  const float* W1    = (const float*)d_in[11];
  const float* b1    = (const float*)d_in[12];
  const float* W2    = (const float*)d_in[13];
  const float* b2    = (const float*)d_in[14];
  float* out = (float*)d_out;

  const int N = in_sizes[0] / 128;
  const int E = in_sizes[1] / 2;
  const int* src = eidx;
  const int* dst = eidx + E;

  // ---- workspace layout: f32 first, then bf16, then fp8, then int ----
  float* ws   = (float*)d_ws;
  float* dinv = ws;                        // N
  float* D    = dinv + (size_t)N;          // N*8  (a_s | a_d)
  float* Vs   = D + (size_t)N*8;           // 256
  float* Vd   = Vs + 256;                  // 256
  unsigned short* A0 = (unsigned short*)(Vd + 256);        // N*64  bf16 (dinv * x @ W_gcn)
  unsigned short* H  = A0 + (size_t)N*64;  // N*64  bf16 (GCN out)
  unsigned short* Y  = H  + (size_t)N*64;  // N*256 bf16 (per-head weighted H sums)
  unsigned short* G  = Y  + (size_t)N*256; // N*256 bf16 (GAT out)
  unsigned short* T  = G  + (size_t)N*256; // N*128 bf16 (P | R)
  unsigned short* S  = T  + (size_t)N*128; // N*64  bf16 (SAGE out)
  unsigned char*  T2 = (unsigned char*)(S + (size_t)N*64); // N*128 fp8 (U | V)
  int* cnt  = (int*)(T2 + (size_t)N*128);  // N
  int* excl = cnt + N;                     // N
  int* bsum = excl + N;                    // 256
  int* offs = bsum + 256;                  // N+1
  int* rank = offs + N + 1;                // E
  int* csr  = rank + E;                    // E

  const int nb = (N + 255) / 256;
  const int gtiles = (N + 63) / 64;
  const int nwb = (N + 15) / 16;          // 4 nodes/wave kernels: 16 nodes per 256-thread block

  // ---- CSR build + dinv + attention basis vectors ----
  hipMemsetAsync(cnt, 0, (size_t)N*sizeof(int), stream);
  k_rank<<<(E+255)/256, 256, 0, stream>>>(dst, cnt, rank, E);
  k_scan1<<<nb, 256, 0, stream>>>(cnt, excl, bsum, N);
  k_scan2v<<<1, 256, 0, stream>>>(bsum, nb, W_gat, att_s, att_d, Vs, Vd);
  k_scan3<<<nb, 256, 0, stream>>>(cnt, excl, bsum, offs, dinv, N, E);
  k_fill<<<(E+255)/256, 256, 0, stream>>>(src, dst, offs, rank, csr, E);

  // ---- GCN: A0 = bf16(dinv * (x @ W_gcn)); H = relu(...); D = GAT logits from H ----
  k_mgemm<128, 64, false, true, false, false, false, false><<<gtiles, 256, 128*64*2, stream>>>(
      x, 128, W_gcn, 64, nullptr, 0, A0, 64, N, dinv, nullptr);
  k_gcn <<<nwb, 256, 0, stream>>>(A0, dinv, b_gcn, offs, csr, H, N);
  k_asdh<<<(N*4+255)/256, 256, 0, stream>>>(H, Vs, Vd, D, N);

  // ---- GAT: softmax + H-domain aggregation -> Y; per-head GEMM + bias + relu -> G ----
  k_gat2<<<(N+7)/8, 256, 0, stream>>>(D, H, offs, csr, Y, N);
  k_mgemm<64, 256, true, false, false, true, true, false><<<gtiles, 256, 64*256*2, stream>>>(
      Y, 256, W_gat, 256, nullptr, 0, G, 256, N, nullptr, b_gat);

  // ---- SAGE: T = bf16(G @ [W_sl | W_sr]); S = relu(mean(P[src]) + b + R) ----
  k_mgemm<256, 128, true, false, true, false, false, false><<<gtiles, 256, 256*128*2, stream>>>(
      G, 256, W_sl, 64, W_sr, 64, T, 128, N, nullptr, nullptr);
  k_sage<<<nwb, 256, 0, stream>>>(T, b_sg, offs, csr, S, N);

  // ---- edge MLP: T2 = fp8(S @ [W1_top | W1_bot]); edge-order eval, coalesced out ----
  k_mgemm<64, 128, true, false, true, false, false, true><<<gtiles, 256, 64*128*2, stream>>>(
      S, 64, W1, 64, W1 + 64*64, 64, T2, 128, N, nullptr, nullptr);
  k_mlp <<<(E+31)/32, 256, 0, stream>>>(T2, b1, W2, b2, src, dst, out, E);
}

// Round 16
// 323.334 us; speedup vs baseline: 1.1965x; 1.0474x over previous
//
#include <hip/hip_runtime.h>
#include <math.h>

// ---------- float4 / bf16 / fp8 helpers ----------
typedef float v2f __attribute__((ext_vector_type(2)));
static __device__ __forceinline__ float4 f4s(float v){ return make_float4(v,v,v,v); }
static __device__ __forceinline__ float4 f4add(float4 a, float4 b){ return make_float4(a.x+b.x,a.y+b.y,a.z+b.z,a.w+b.w); }
static __device__ __forceinline__ float4 f4max(float4 a, float4 b){ return make_float4(fmaxf(a.x,b.x),fmaxf(a.y,b.y),fmaxf(a.z,b.z),fmaxf(a.w,b.w)); }
static __device__ __forceinline__ float4 f4scale(float4 a, float s){ return make_float4(a.x*s,a.y*s,a.z*s,a.w*s); }
static __device__ __forceinline__ float4 f4fma(float4 acc, float s, float4 b){
  acc.x += s*b.x; acc.y += s*b.y; acc.z += s*b.z; acc.w += s*b.w; return acc;
}
static __device__ __forceinline__ float4 f4relu(float4 a){ return f4max(a, f4s(0.f)); }
static __device__ __forceinline__ float4 f4leaky(float4 a){
  return make_float4(a.x>0.f?a.x:0.2f*a.x, a.y>0.f?a.y:0.2f*a.y, a.z>0.f?a.z:0.2f*a.z, a.w>0.f?a.w:0.2f*a.w);
}
static __device__ __forceinline__ float4 f4expf(float4 a){ return make_float4(__expf(a.x),__expf(a.y),__expf(a.z),__expf(a.w)); }
static __device__ __forceinline__ unsigned short f2bf(float f){
  unsigned int u = __float_as_uint(f);
  unsigned int r = (u + 0x7fffu + ((u >> 16) & 1u)) >> 16;
  return (unsigned short)r;
}
static __device__ __forceinline__ ushort4 f2bf4(float4 f){
  ushort4 r; r.x=f2bf(f.x); r.y=f2bf(f.y); r.z=f2bf(f.z); r.w=f2bf(f.w); return r;
}
// bf16x4 (as uint2) -> float4 : 4 VALU ops
static __device__ __forceinline__ float4 bfu2f4(uint2 u){
  return make_float4(__uint_as_float(u.x << 16), __uint_as_float(u.x & 0xffff0000u),
                     __uint_as_float(u.y << 16), __uint_as_float(u.y & 0xffff0000u));
}
static __device__ __forceinline__ float4 bfu2f4_lo(uint4 u){ return bfu2f4(make_uint2(u.x, u.y)); }
static __device__ __forceinline__ float4 bfu2f4_hi(uint4 u){ return bfu2f4(make_uint2(u.z, u.w)); }

typedef __attribute__((ext_vector_type(8))) unsigned short u16x8;
static __device__ __forceinline__ u16x8 f2bf8(float4 a, float4 b){
  u16x8 r;
  r[0]=f2bf(a.x); r[1]=f2bf(a.y); r[2]=f2bf(a.z); r[3]=f2bf(a.w);
  r[4]=f2bf(b.x); r[5]=f2bf(b.y); r[6]=f2bf(b.z); r[7]=f2bf(b.w);
  return r;
}
// reduce two float4 across 2 groups at lane stride 8
static __device__ __forceinline__ void red2(float4& a, float4& b){
  a.x += __shfl_xor(a.x, 8); a.y += __shfl_xor(a.y, 8);
  a.z += __shfl_xor(a.z, 8); a.w += __shfl_xor(a.w, 8);
  b.x += __shfl_xor(b.x, 8); b.y += __shfl_xor(b.y, 8);
  b.z += __shfl_xor(b.z, 8); b.w += __shfl_xor(b.w, 8);
}
// fp8 (OCP e4m3) pack/unpack
static __device__ __forceinline__ unsigned char f2fp8(float v){
  return (unsigned char)(__builtin_amdgcn_cvt_pk_fp8_f32(v, v, 0, false) & 0xff);
}
static __device__ __forceinline__ unsigned int f4_fp8x4(float4 v){
  unsigned int r = __builtin_amdgcn_cvt_pk_fp8_f32(v.x, v.y, 0, false);
  r = __builtin_amdgcn_cvt_pk_fp8_f32(v.z, v.w, r, true);
  return r;
}
static __device__ __forceinline__ float4 fp8x4_f4(unsigned int q){
  v2f lo = __builtin_amdgcn_cvt_pk_f32_fp8(q, false);
  v2f hi = __builtin_amdgcn_cvt_pk_f32_fp8(q, true);
  return make_float4(lo[0], lo[1], hi[0], hi[1]);
}

// ---------- MFMA types ----------
typedef __attribute__((ext_vector_type(8))) short bf16x8;   // 8 bf16 = 4 VGPRs
typedef __attribute__((ext_vector_type(4))) float f32x4;

// ---------- CSR build ----------
__global__ __launch_bounds__(256) void k_rank(const int* __restrict__ dst, int* __restrict__ cnt,
                                              int* __restrict__ rank, int E){
  int t = blockIdx.x*256 + threadIdx.x;
  if (t < E) rank[t] = atomicAdd(&cnt[dst[t]], 1);
}
__global__ __launch_bounds__(256) void k_scan1(const int* __restrict__ cnt, int* __restrict__ excl,
                                               int* __restrict__ bsum, int n){
  __shared__ int sc[256];
  int t = threadIdx.x; int i = blockIdx.x*256 + t;
  int v = (i<n)?cnt[i]:0;
  sc[t]=v; __syncthreads();
  for (int o=1;o<256;o<<=1){ int a=(t>=o)?sc[t-o]:0; __syncthreads(); sc[t]+=a; __syncthreads(); }
  if (i<n) excl[i] = sc[t]-v;
  if (t==255) bsum[blockIdx.x] = sc[t];
}
// scan of block sums + (fused) GAT attention basis vectors Vs/Vd
__global__ __launch_bounds__(256) void k_scan2v(int* __restrict__ bsum, int nb,
                                                const float* __restrict__ Wg, const float* __restrict__ as,
                                                const float* __restrict__ ad, float* __restrict__ Vs,
                                                float* __restrict__ Vd){
  __shared__ int sc[256];
  int t = threadIdx.x;
  int v = (t<nb)?bsum[t]:0;
  sc[t]=v; __syncthreads();
  for (int o=1;o<256;o<<=1){ int a=(t>=o)?sc[t-o]:0; __syncthreads(); sc[t]+=a; __syncthreads(); }
  if (t<nb) bsum[t] = sc[t]-v;
  int h = t >> 6, k = t & 63;
  float s = 0.f, d = 0.f;
  const float* wr = Wg + (size_t)k*256 + h*64;
  const float* ar = as + h*64;
  const float* dr = ad + h*64;
  for (int c = 0; c < 64; ++c){ float w = wr[c]; s += w*ar[c]; d += w*dr[c]; }
  Vs[t] = s; Vd[t] = d;
}
__global__ __launch_bounds__(256) void k_scan3(const int* __restrict__ cnt, const int* __restrict__ excl,
                                               const int* __restrict__ bsum, int* __restrict__ offs,
                                               float* __restrict__ dinv, int n, int E){
  int i = blockIdx.x*256 + threadIdx.x;
  if (i < n){
    int o = excl[i] + bsum[blockIdx.x];
    offs[i] = o;
    dinv[i] = rsqrtf((float)cnt[i] + 1.0f);   // deg includes self-loop
    if (i == 0) offs[n] = E;
  }
}
// scatter-only fill: no atomic, store can fire-and-forget.
__global__ __launch_bounds__(256) void k_fill(const int* __restrict__ src, const int* __restrict__ dst,
                                              const int* __restrict__ offs, const int* __restrict__ rank,
                                              int* __restrict__ csr, int E){
  int t = blockIdx.x*256 + threadIdx.x;
  if (t < E) csr[offs[dst[t]] + rank[t]] = src[t];
}

// ---------- GAT logits from H (bf16): D[nd][h] = H.Vs[h], D[nd][4+h] = H.Vd[h] ----------
__global__ __launch_bounds__(256) void k_asdh(const unsigned short* __restrict__ Hh,
                                              const float* __restrict__ Vs, const float* __restrict__ Vd,
                                              float* __restrict__ D, int n){
  __shared__ float vs[256], vd[256];
  int t = threadIdx.x;
  vs[t] = Vs[t]; vd[t] = Vd[t];
  __syncthreads();
  int idx = blockIdx.x*256 + t;
  if (idx >= n*4) return;
  int nd = idx >> 2, h = idx & 3;
  const unsigned short* hr = Hh + (size_t)nd*64;
  const float* vsr = vs + h*64;
  const float* vdr = vd + h*64;
  float s = 0.f, d = 0.f;
  #pragma unroll
  for (int k = 0; k < 8; ++k){
    uint4 u = *(const uint4*)(hr + k*8);
    float4 lo = bfu2f4_lo(u), hi = bfu2f4_hi(u);
    const float* a = vsr + k*8;
    const float* b = vdr + k*8;
    s += lo.x*a[0]+lo.y*a[1]+lo.z*a[2]+lo.w*a[3] + hi.x*a[4]+hi.y*a[5]+hi.z*a[6]+hi.w*a[7];
    d += lo.x*b[0]+lo.y*b[1]+lo.z*b[2]+lo.w*b[3] + hi.x*b[4]+hi.y*b[5]+hi.z*b[6]+hi.w*b[7];
  }
  D[(size_t)nd*8 + h]     = s;
  D[(size_t)nd*8 + 4 + h] = d;
}

// ---------- MFMA GEMM: in[n,K] @ W; optional bf16 out + fp8 shadow out ----------
template<int K, int Cout, bool IBF16, bool SCALE, bool DUAL, bool H4, bool BRELU, bool OB16, bool O8>
__global__ __launch_bounds__(256) void k_mgemm(const void* __restrict__ in, int ldin,
                                               const float* __restrict__ Wa, int ldwa,
                                               const float* __restrict__ Wb, int ldwb,
                                               unsigned short* __restrict__ out,
                                               unsigned char* __restrict__ out8, int ldout,
                                               int n, const float* __restrict__ rowscale,
                                               const float* __restrict__ bias){
  constexpr int CC = Cout >> 4;       // 16-col chunks
  constexpr int KB = K >> 5;          // 32-k blocks
  constexpr int NH = H4 ? 4 : 1;
  extern __shared__ unsigned short wb[];
  int tid = threadIdx.x;
  constexpr int nslots = KB*CC*64;
  for (int s = tid; s < nslots; s += 256){
    int l = s & 63;
    int f = s >> 6;                   // frag = kb*CC + cc
    int cc = f % CC, kb = f / CC;
    int c  = cc*16 + (l & 15);
    int kr = kb*32 + ((l >> 4) << 3);
    const float* wp; int ld;
    if (DUAL && c >= (Cout/2)){ wp = Wb + (size_t)kr*ldwb + (c - Cout/2); ld = ldwb; }
    else                      { wp = Wa + (size_t)kr*ldwa + c;            ld = ldwa; }
    unsigned short* dp = &wb[s*8];
    #pragma unroll
    for (int j = 0; j < 8; ++j) dp[j] = f2bf(wp[(size_t)j*ld]);
  }
  __syncthreads();
  int wv = tid >> 6, l = tid & 63;
  int lrow = l & 15;
  int lk = (l >> 4) << 3;
  int ngrp = (n + 63) >> 6;
  const unsigned short* inb = (const unsigned short*)in;
  const float* inf = (const float*)in;
  for (int g = blockIdx.x; g < ngrp; g += gridDim.x){
    int r0 = (g << 6) + (wv << 4);
    int m = r0 + lrow;
    bf16x8 afr[NH][KB];
    #pragma unroll
    for (int h = 0; h < NH; ++h){
      #pragma unroll
      for (int kb = 0; kb < KB; ++kb){
        bf16x8 a = {0,0,0,0,0,0,0,0};
        if (m < n){
          int off = (H4 ? h*64 : 0) + kb*32 + lk;
          if (IBF16){
            a = *(const bf16x8*)(inb + (size_t)m*ldin + off);
          } else {
            const float* p = inf + (size_t)m*ldin + off;
            float4 f0 = *(const float4*)p;
            float4 f1 = *(const float4*)(p + 4);
            a[0]=(short)f2bf(f0.x); a[1]=(short)f2bf(f0.y); a[2]=(short)f2bf(f0.z); a[3]=(short)f2bf(f0.w);
            a[4]=(short)f2bf(f1.x); a[5]=(short)f2bf(f1.y); a[6]=(short)f2bf(f1.z); a[7]=(short)f2bf(f1.w);
          }
        }
        afr[h][kb] = a;
      }
    }
    int rbase = r0 + ((l >> 4) << 2);
    float sc[4];
    if (SCALE){
      #pragma unroll
      for (int r = 0; r < 4; ++r) sc[r] = (rbase + r < n) ? rowscale[rbase + r] : 0.f;
    }
    #pragma unroll
    for (int cc = 0; cc < CC; ++cc){
      f32x4 acc = {0.f, 0.f, 0.f, 0.f};
      constexpr int hstep = H4 ? 1 : 0;
      int hh = hstep ? (cc >> 2) : 0;
      #pragma unroll
      for (int kb = 0; kb < KB; ++kb){
        bf16x8 b = *(const bf16x8*)&wb[((kb*CC + cc)*64 + l)*8];
        acc = __builtin_amdgcn_mfma_f32_16x16x32_bf16(afr[hh][kb], b, acc, 0, 0, 0);
      }
      int c = cc*16 + lrow;
      float bv = BRELU ? bias[c] : 0.f;
      #pragma unroll
      for (int r = 0; r < 4; ++r){
        int rr = rbase + r;
        if (rr < n){
          float v = acc[r];
          if (SCALE) v *= sc[r];
          if (BRELU) v = fmaxf(v + bv, 0.f);
          if (OB16) out[(size_t)rr*ldout + c] = f2bf(v);
          if (O8)   out8[(size_t)rr*ldout + c] = f2fp8(v);
        }
      }
    }
  }
}

// ---------- GCN aggregation: 4 nodes/wave, 16 lanes/node; gathers fp8 A8 rows (64 B) ----------
// A8 rows pre-scaled by dinv[src]; H = relu(dinv_d*(sum+self) + b) -> bf16 H + fp8 H8.
__global__ __launch_bounds__(256) void k_gcn(const unsigned char* __restrict__ a8, const float* __restrict__ dinv,
                                             const float* __restrict__ b, const int* __restrict__ offs,
                                             const int* __restrict__ csr, unsigned short* __restrict__ h,
                                             unsigned char* __restrict__ h8, int n){
  int l = threadIdx.x & 63;
  int node = (((blockIdx.x*256 + threadIdx.x) >> 6) << 2) + (l >> 4);
  int l15 = l & 15;
  int grp = l15 >> 3, sub = l15 & 7;
  bool ok = node < n;
  int beg = 0, end = 0;
  float di = 0.f;
  if (ok){ beg = offs[node]; end = offs[node+1]; di = dinv[node]; }
  float4 aL0 = f4s(0.f), aH0 = f4s(0.f), aL1 = f4s(0.f), aH1 = f4s(0.f);
  int i = beg + grp;
  for (; i + 2 < end; i += 4){
    int s0 = csr[i], s1 = csr[i+2];
    uint2 u0 = *(const uint2*)(a8 + (size_t)s0*64 + (sub<<3));
    uint2 u1 = *(const uint2*)(a8 + (size_t)s1*64 + (sub<<3));
    aL0 = f4add(aL0, fp8x4_f4(u0.x)); aH0 = f4add(aH0, fp8x4_f4(u0.y));
    aL1 = f4add(aL1, fp8x4_f4(u1.x)); aH1 = f4add(aH1, fp8x4_f4(u1.y));
  }
  if (i < end){
    int s0 = csr[i];
    uint2 u0 = *(const uint2*)(a8 + (size_t)s0*64 + (sub<<3));
    aL0 = f4add(aL0, fp8x4_f4(u0.x)); aH0 = f4add(aH0, fp8x4_f4(u0.y));
  }
  float4 aL = f4add(aL0, aL1), aH = f4add(aH0, aH1);
  red2(aL, aH);
  if (ok && grp == 0){
    uint2 us = *(const uint2*)(a8 + (size_t)node*64 + (sub<<3));   // self (pre-scaled)
    aL = f4add(aL, fp8x4_f4(us.x)); aH = f4add(aH, fp8x4_f4(us.y));
    float4 b0 = *(const float4*)(b + (sub<<3));
    float4 b1 = *(const float4*)(b + (sub<<3) + 4);
    float4 r0 = f4relu(f4fma(b0, di, aL));
    float4 r1 = f4relu(f4fma(b1, di, aH));
    *(u16x8*)(h + (size_t)node*64 + (sub<<3)) = f2bf8(r0, r1);
    uint2 q; q.x = f4_fp8x4(r0); q.y = f4_fp8x4(r1);
    *(uint2*)(h8 + (size_t)node*64 + (sub<<3)) = q;
  }
}

// ---------- fused GAT softmax + H-domain aggregation: 2 nodes/wave; gathers fp8 H8 (64 B rows) ----------
#define GAT_CAP 128
__global__ __launch_bounds__(256) void k_gat2(const float* __restrict__ D, const unsigned char* __restrict__ H8,
                                              const int* __restrict__ offs, const int* __restrict__ csr,
                                              unsigned short* __restrict__ Y, int n){
  __shared__ float wl[8][GAT_CAP*4];
  __shared__ int   sl[8][GAT_CAP];
  int hw = threadIdx.x >> 5;                 // half-wave index in block (0..7)
  int node = (blockIdx.x*256 + threadIdx.x) >> 5;
  int l5 = threadIdx.x & 31;
  if (node >= n) return;
  int beg = offs[node], end = offs[node+1];
  int deg = end - beg;
  float4 ed  = *(const float4*)(D + (size_t)node*8 + 4);
  float4 es0 = *(const float4*)(D + (size_t)node*8);
  float4 wself = f4expf(f4leaky(f4add(es0, ed)));
  // phase A: per-edge exp weights + src byte-offset -> LDS (first GAT_CAP), z accumulation (all)
  float4 z4 = f4s(0.f);
  for (int i = beg + l5; i < end; i += 32){
    int s = csr[i];
    float4 w = f4expf(f4leaky(f4add(*(const float4*)(D + (size_t)s*8), ed)));
    int li = i - beg;
    if (li < GAT_CAP){ *(float4*)&wl[hw][li<<2] = w; sl[hw][li] = s << 6; }  // 64 B per H8 row
    z4 = f4add(z4, w);
  }
  for (int m = 1; m < 32; m <<= 1){
    z4.x += __shfl_xor(z4.x, m); z4.y += __shfl_xor(z4.y, m);
    z4.z += __shfl_xor(z4.z, m); z4.w += __shfl_xor(z4.w, m);
  }
  z4 = f4add(z4, wself);
  // phase C: 2 edge-groups x 16 lanes per node; lane covers 4 cols (4 B) of the 64-col H8 row
  int grp = l5 >> 4;
  int sub = l5 & 15;
  int c0b = sub << 2;           // byte offset of 4-col fp8 slice
  float4 a0 = f4s(0.f), a1 = f4s(0.f), a2 = f4s(0.f), a3 = f4s(0.f);  // per-head accumulators
  int nl = deg < GAT_CAP ? deg : GAT_CAP;
  int i = grp;
  for (; i + 2 < nl; i += 4){
    int o0 = sl[hw][i], o1 = sl[hw][i+2];
    float4 w0 = *(const float4*)&wl[hw][i<<2];
    float4 w1 = *(const float4*)&wl[hw][(i+2)<<2];
    unsigned int q0 = *(const unsigned int*)(H8 + o0 + c0b);
    unsigned int q1 = *(const unsigned int*)(H8 + o1 + c0b);
    float4 f0 = fp8x4_f4(q0);
    float4 f1 = fp8x4_f4(q1);
    a0 = f4fma(a0, w0.x, f0); a1 = f4fma(a1, w0.y, f0);
    a2 = f4fma(a2, w0.z, f0); a3 = f4fma(a3, w0.w, f0);
    a0 = f4fma(a0, w1.x, f1); a1 = f4fma(a1, w1.y, f1);
    a2 = f4fma(a2, w1.z, f1); a3 = f4fma(a3, w1.w, f1);
  }
  if (i < nl){
    float4 w0 = *(const float4*)&wl[hw][i<<2];
    float4 f0 = fp8x4_f4(*(const unsigned int*)(H8 + sl[hw][i] + c0b));
    a0 = f4fma(a0, w0.x, f0); a1 = f4fma(a1, w0.y, f0);
    a2 = f4fma(a2, w0.z, f0); a3 = f4fma(a3, w0.w, f0);
  }
  for (int j = nl + grp; j < deg; j += 2){   // LDS overflow fallback (essentially never)
    int s = csr[beg+j];
    float4 e = f4leaky(f4add(*(const float4*)(D + (size_t)s*8), ed));
    float4 w = f4expf(e);
    float4 f0 = fp8x4_f4(*(const unsigned int*)(H8 + ((size_t)s << 6) + c0b));
    a0 = f4fma(a0, w.x, f0); a1 = f4fma(a1, w.y, f0);
    a2 = f4fma(a2, w.z, f0); a3 = f4fma(a3, w.w, f0);
  }
  // cross-group reduce (lane stride 16, stays within half-wave)
  a0.x += __shfl_xor(a0.x, 16); a0.y += __shfl_xor(a0.y, 16); a0.z += __shfl_xor(a0.z, 16); a0.w += __shfl_xor(a0.w, 16);
  a1.x += __shfl_xor(a1.x, 16); a1.y += __shfl_xor(a1.y, 16); a1.z += __shfl_xor(a1.z, 16); a1.w += __shfl_xor(a1.w, 16);
  a2.x += __shfl_xor(a2.x, 16); a2.y += __shfl_xor(a2.y, 16); a2.z += __shfl_xor(a2.z, 16); a2.w += __shfl_xor(a2.w, 16);
  a3.x += __shfl_xor(a3.x, 16); a3.y += __shfl_xor(a3.y, 16); a3.z += __shfl_xor(a3.z, 16); a3.w += __shfl_xor(a3.w, 16);
  if (grp == 0){
    float4 fs = fp8x4_f4(*(const unsigned int*)(H8 + ((size_t)node << 6) + c0b));   // self term
    a0 = f4fma(a0, wself.x, fs);
    a1 = f4fma(a1, wself.y, fs);
    a2 = f4fma(a2, wself.z, fs);
    a3 = f4fma(a3, wself.w, fs);
    a0 = f4scale(a0, 1.f/(z4.x + 1e-16f));
    a1 = f4scale(a1, 1.f/(z4.y + 1e-16f));
    a2 = f4scale(a2, 1.f/(z4.z + 1e-16f));
    a3 = f4scale(a3, 1.f/(z4.w + 1e-16f));
    // Y layout: head-major [nd][h*64 + c], bf16
    unsigned short* yp = Y + (size_t)node*256 + (sub << 2);
    *(ushort4*)(yp)       = f2bf4(a0);
    *(ushort4*)(yp + 64)  = f2bf4(a1);
    *(ushort4*)(yp + 128) = f2bf4(a2);
    *(ushort4*)(yp + 192) = f2bf4(a3);
  }
}

// ---------- SAGE aggregation: 4 nodes/wave, 16 lanes/node; gathers fp8 T8 P-half (64 B) ----------
// Root term R read from bf16 T (coalesced, full precision).
__global__ __launch_bounds__(256) void k_sage(const unsigned char* __restrict__ T8, const unsigned short* __restrict__ T,
                                              const float* __restrict__ b, const int* __restrict__ offs,
                                              const int* __restrict__ csr, unsigned short* __restrict__ S, int n){
  int l = threadIdx.x & 63;
  int node = (((blockIdx.x*256 + threadIdx.x) >> 6) << 2) + (l >> 4);
  int l15 = l & 15;
  int grp = l15 >> 3, sub = l15 & 7;
  bool ok = node < n;
  int beg = 0, end = 0;
  if (ok){ beg = offs[node]; end = offs[node+1]; }
  float4 aL0 = f4s(0.f), aH0 = f4s(0.f), aL1 = f4s(0.f), aH1 = f4s(0.f);
  int i = beg + grp;
  for (; i + 2 < end; i += 4){
    int s0 = csr[i], s1 = csr[i+2];
    uint2 u0 = *(const uint2*)(T8 + (size_t)s0*128 + (sub<<3));
    uint2 u1 = *(const uint2*)(T8 + (size_t)s1*128 + (sub<<3));
    aL0 = f4add(aL0, fp8x4_f4(u0.x)); aH0 = f4add(aH0, fp8x4_f4(u0.y));
    aL1 = f4add(aL1, fp8x4_f4(u1.x)); aH1 = f4add(aH1, fp8x4_f4(u1.y));
  }
  if (i < end){
    int s0 = csr[i];
    uint2 u0 = *(const uint2*)(T8 + (size_t)s0*128 + (sub<<3));
    aL0 = f4add(aL0, fp8x4_f4(u0.x)); aH0 = f4add(aH0, fp8x4_f4(u0.y));
  }
  float4 aL = f4add(aL0, aL1), aH = f4add(aH0, aH1);
  red2(aL, aH);
  if (ok && grp == 0){
    float minv = 1.f / fmaxf((float)(end - beg), 1.f);
    uint4 ur = *(const uint4*)(T + (size_t)node*128 + 64 + (sub<<3));
    float4 b0 = *(const float4*)(b + (sub<<3));
    float4 b1 = *(const float4*)(b + (sub<<3) + 4);
    float4 r0 = f4relu(f4add(f4fma(b0, minv, aL), bfu2f4_lo(ur)));
    float4 r1 = f4relu(f4add(f4fma(b1, minv, aH), bfu2f4_hi(ur)));
    *(u16x8*)(S + (size_t)node*64 + (sub<<3)) = f2bf8(r0, r1);
  }
}

// ---------- edge MLP, edge-order: 8 lanes/edge; T2 = [U|V] fp8 rows of 128 B ----------
__global__ __launch_bounds__(256) void k_mlp(const unsigned char* __restrict__ T2,
                                             const float* __restrict__ b1, const float* __restrict__ W2,
                                             const float* __restrict__ b2, const int* __restrict__ src,
                                             const int* __restrict__ dst, float* __restrict__ out, int E){
  int t = threadIdx.x;
  int e = blockIdx.x*32 + (t >> 3);
  if (e >= E) return;
  int sub = t & 7;
  int s = src[e], d = dst[e];
  uint2 uu = *(const uint2*)(T2 + (size_t)s*128 + (sub<<3));        // 8 fp8 of U[s]
  uint2 vv = *(const uint2*)(T2 + (size_t)d*128 + 64 + (sub<<3));   // 8 fp8 of V[d]
  float4 u0 = fp8x4_f4(uu.x), u1 = fp8x4_f4(uu.y);
  float4 v0 = fp8x4_f4(vv.x), v1 = fp8x4_f4(vv.y);
  float4 bb0 = *(const float4*)(b1 + (sub<<3));
  float4 bb1 = *(const float4*)(b1 + (sub<<3) + 4);
  float4 w0 = *(const float4*)(W2 + (sub<<3));
  float4 w1 = *(const float4*)(W2 + (sub<<3) + 4);
  float4 ta = f4relu(f4add(f4add(u0, v0), bb0));
  float4 tb = f4relu(f4add(f4add(u1, v1), bb1));
  float p = ta.x*w0.x + ta.y*w0.y + ta.z*w0.z + ta.w*w0.w
          + tb.x*w1.x + tb.y*w1.y + tb.z*w1.z + tb.w*w1.w;
  p += __shfl_xor(p, 1);
  p += __shfl_xor(p, 2);
  p += __shfl_xor(p, 4);
  if (sub == 0) out[e] = 1.f / (1.f + __expf(-(p + b2[0])));
}

extern "C" void kernel_launch(void* const* d_in, const int* in_sizes, int n_in,
                              void* d_out, int out_size, void* d_ws, size_t ws_size,
                              hipStream_t stream){
  const float* x     = (const float*)d_in[0];
  const int*   eidx  = (const int*)  d_in[1];
  const float* W_gcn = (const float*)d_in[2];
  const float* b_gcn = (const float*)d_in[3];
  const float* W_gat = (const float*)d_in[4];
  const float* att_s = (const float*)d_in[5];
  const float* att_d = (const float*)d_in[6];
  const float* b_gat = (const float*)d_in[7];
  const float* W_sl  = (const float*)d_in[8];
  const float* b_sg  = (const float*)d_in[9];
  const float* W_sr  = (const float*)d_in[10];
  const float* W1    = (const float*)d_in[11];
  const float* b1    = (const float*)d_in[12];
  const float* W2    = (const float*)d_in[13];
  const float* b2    = (const float*)d_in[14];
  float* out = (float*)d_out;

  const int N = in_sizes[0] / 128;
  const int E = in_sizes[1] / 2;
  const int* src = eidx;
  const int* dst = eidx + E;

  // ---- workspace layout: f32, then bf16, then fp8, then int ----
  float* ws   = (float*)d_ws;
  float* dinv = ws;                        // N
  float* D    = dinv + (size_t)N;          // N*8  (a_s | a_d)
  float* Vs   = D + (size_t)N*8;           // 256
  float* Vd   = Vs + 256;                  // 256
  unsigned short* A0 = (unsigned short*)(Vd + 256);        // N*64  bf16 (unused slot kept for alignment)
  unsigned short* H  = A0 + (size_t)N*64;  // N*64  bf16 (GCN out)
  unsigned short* Y  = H  + (size_t)N*64;  // N*256 bf16 (per-head weighted H sums)
  unsigned short* G  = Y  + (size_t)N*256; // N*256 bf16 (GAT out)
  unsigned short* T  = G  + (size_t)N*256; // N*128 bf16 (P | R)
  unsigned short* S  = T  + (size_t)N*128; // N*64  bf16 (SAGE out)
  unsigned char*  A8 = (unsigned char*)(S + (size_t)N*64); // N*64  fp8 (dinv * x @ W_gcn)
  unsigned char*  H8 = A8 + (size_t)N*64;  // N*64  fp8 (GCN out shadow)
  unsigned char*  T8 = H8 + (size_t)N*64;  // N*128 fp8 (P | R shadow)
  unsigned char*  T2 = T8 + (size_t)N*128; // N*128 fp8 (U | V)
  int* cnt  = (int*)(T2 + (size_t)N*128);  // N
  int* excl = cnt + N;                     // N
  int* bsum = excl + N;                    // 256
  int* offs = bsum + 256;                  // N+1
  int* rank = offs + N + 1;                // E
  int* csr  = rank + E;                    // E

  const int nb = (N + 255) / 256;
  const int gtiles = (N + 63) / 64;
  const int nwb = (N + 15) / 16;          // 4 nodes/wave kernels

  // ---- CSR build + dinv + attention basis vectors ----
  hipMemsetAsync(cnt, 0, (size_t)N*sizeof(int), stream);
  k_rank<<<(E+255)/256, 256, 0, stream>>>(dst, cnt, rank, E);
  k_scan1<<<nb, 256, 0, stream>>>(cnt, excl, bsum, N);
  k_scan2v<<<1, 256, 0, stream>>>(bsum, nb, W_gat, att_s, att_d, Vs, Vd);
  k_scan3<<<nb, 256, 0, stream>>>(cnt, excl, bsum, offs, dinv, N, E);
  k_fill<<<(E+255)/256, 256, 0, stream>>>(src, dst, offs, rank, csr, E);

  // ---- GCN: A8 = fp8(dinv * (x @ W_gcn)); H,H8 = relu(...); D = GAT logits from H ----
  k_mgemm<128, 64, false, true, false, false, false, false, true><<<gtiles, 256, 128*64*2, stream>>>(
      x, 128, W_gcn, 64, nullptr, 0, nullptr, A8, 64, N, dinv, nullptr);
  k_gcn <<<nwb, 256, 0, stream>>>(A8, dinv, b_gcn, offs, csr, H, H8, N);
  k_asdh<<<(N*4+255)/256, 256, 0, stream>>>(H, Vs, Vd, D, N);

  // ---- GAT: softmax + fp8 H-domain aggregation -> Y; per-head GEMM + bias + relu -> G ----
  k_gat2<<<(N+7)/8, 256, 0, stream>>>(D, H8, offs, csr, Y, N);
  k_mgemm<64, 256, true, false, false, true, true, true, false><<<gtiles, 256, 64*256*2, stream>>>(
      Y, 256, W_gat, 256, nullptr, 0, G, nullptr, 256, N, nullptr, b_gat);

  // ---- SAGE: T bf16 + T8 fp8 = G @ [W_sl | W_sr]; S = relu(mean(P8[src]) + b + R) ----
  k_mgemm<256, 128, true, false, true, false, false, true, true><<<gtiles, 256, 256*128*2, stream>>>(
      G, 256, W_sl, 64, W_sr, 64, T, T8, 128, N, nullptr, nullptr);
  k_sage<<<nwb, 256, 0, stream>>>(T8, T, b_sg, offs, csr, S, N);

  // ---- edge MLP: T2 = fp8(S @ [W1_top | W1_bot]); edge-order eval, coalesced out ----
  k_mgemm<64, 128, true, false, true, false, false, false, true><<<gtiles, 256, 64*128*2, stream>>>(
      S, 64, W1, 64, W1 + 64*64, 64, nullptr, T2, 128, N, nullptr, nullptr);
  k_mlp <<<(E+31)/32, 256, 0, stream>>>(T2, b1, W2, b2, src, dst, out, E);
}